// Round 1
// baseline (2735.554 us; speedup 1.0000x reference)
//
#include <hip/hip_runtime.h>
#include <hip/hip_bf16.h>

// Problem constants
#define NB   4
#define NT   4096
#define BT   16384   // NB*NT
#define NDIM 1024
#define NH   16
#define NDH  64

using u16 = unsigned short;
typedef __bf16 bf16x8 __attribute__((ext_vector_type(8)));
typedef float f32x4 __attribute__((ext_vector_type(4)));
typedef unsigned short u16x8 __attribute__((ext_vector_type(8)));
typedef unsigned short u16x4 __attribute__((ext_vector_type(4)));

__device__ __forceinline__ float bf2f(u16 b) { return __uint_as_float(((unsigned)b) << 16); }
__device__ __forceinline__ u16 f2bf(float f) {
  return __builtin_bit_cast(u16, __float2bfloat16(f));
}

// ---------------- convert fp32 -> bf16 (vectorized) ----------------
__global__ __launch_bounds__(256) void k_f32_to_bf16(const float* __restrict__ in,
                                                     u16* __restrict__ out, long n4) {
  long i = (long)blockIdx.x * blockDim.x + threadIdx.x;
  if (i >= n4) return;
  float4 f = reinterpret_cast<const float4*>(in)[i];
  u16x4 o;
  o.x = f2bf(f.x); o.y = f2bf(f.y); o.z = f2bf(f.z); o.w = f2bf(f.w);
  reinterpret_cast<u16x4*>(out)[i] = o;
}

// ---------------- build padded gate weight matrix (128 x 1024 bf16) ----------------
__global__ __launch_bounds__(256) void k_build_wgb(const float* __restrict__ Wg,
                                                   const float* __restrict__ Wb,
                                                   u16* __restrict__ out) {
  int i = blockIdx.x * 256 + threadIdx.x;      // 128*1024 threads
  int row = i >> 10, col = i & 1023;
  float f = 0.f;
  if (row < 16)       f = Wg[row * 1024 + col];
  else if (row < 32)  f = Wb[(row - 16) * 1024 + col];
  out[i] = f2bf(f);
}

// ---------------- global_load_lds helper ----------------
typedef unsigned int u32_as1 __attribute__((address_space(1)));
typedef unsigned int u32_as3 __attribute__((address_space(3)));
__device__ __forceinline__ void gload_lds16(const u16* g, u16* l) {
  __builtin_amdgcn_global_load_lds((const u32_as1*)g, (u32_as3*)l, 16, 0, 0);
}

// ---------------- bf16 GEMM: C(MxN) = A(MxK) @ B(NxK)^T ----------------
// m97-style: 128x128 tile, BK=32, 4 waves (2x2 of 64x64), 16x16x32 MFMA
template <typename OutT>
__global__ __launch_bounds__(256) void k_gemm_bt(const u16* __restrict__ A,
                                                 const u16* __restrict__ B,
                                                 OutT* __restrict__ C,
                                                 int M, int N, int K) {
  constexpr int BM = 128, BN = 128, BK = 32;
  __shared__ __align__(16) u16 As[BM * BK];
  __shared__ __align__(16) u16 Bs[BN * BK];
  const int tid = threadIdx.x;
  const int l = tid & 63, w = tid >> 6;
  const int tn = blockIdx.x, tm = blockIdx.y;
  const long a0 = (long)tm * BM * K;
  const long b0 = (long)tn * BN * K;
  const int srow = tid >> 2;            // 0..63 (row within 64-row staging pass)
  const int scol = (tid & 3) << 3;      // 0,8,16,24 (bf16 elems)
  const int wrow = (w >> 1) << 6;       // 0 or 64
  const int wcol = (w & 1) << 6;        // 0 or 64
  const int fr = l & 15, fq = l >> 4;

  f32x4 acc[4][4];
#pragma unroll
  for (int m = 0; m < 4; ++m)
#pragma unroll
    for (int n = 0; n < 4; ++n) acc[m][n] = f32x4{0.f, 0.f, 0.f, 0.f};

  for (int kk = 0; kk < K; kk += BK) {
    __syncthreads();
    const u16* gA = A + a0 + (long)srow * K + kk + scol;
    const u16* gB = B + b0 + (long)srow * K + kk + scol;
    gload_lds16(gA,           &As[(w * 16) * BK]);
    gload_lds16(gA + 64 * (long)K, &As[(64 + w * 16) * BK]);
    gload_lds16(gB,           &Bs[(w * 16) * BK]);
    gload_lds16(gB + 64 * (long)K, &Bs[(64 + w * 16) * BK]);
    __syncthreads();   // drains vmcnt before barrier -> LDS tiles ready

    bf16x8 af[4], bfv[4];
#pragma unroll
    for (int m = 0; m < 4; ++m)
      af[m] = *(const bf16x8*)&As[(wrow + m * 16 + fr) * BK + (fq << 3)];
#pragma unroll
    for (int n = 0; n < 4; ++n)
      bfv[n] = *(const bf16x8*)&Bs[(wcol + n * 16 + fr) * BK + (fq << 3)];
#pragma unroll
    for (int m = 0; m < 4; ++m)
#pragma unroll
      for (int n = 0; n < 4; ++n)
        acc[m][n] = __builtin_amdgcn_mfma_f32_16x16x32_bf16(af[m], bfv[n], acc[m][n], 0, 0, 0);
  }

#pragma unroll
  for (int m = 0; m < 4; ++m) {
#pragma unroll
    for (int n = 0; n < 4; ++n) {
      const int r0 = tm * BM + wrow + m * 16 + fq * 4;
      const int c  = tn * BN + wcol + n * 16 + fr;
#pragma unroll
      for (int r = 0; r < 4; ++r) {
        float v = acc[m][n][r];
        long idx = (long)(r0 + r) * N + c;
        if constexpr (sizeof(OutT) == 2) C[idx] = f2bf(v);
        else                             C[idx] = v;
      }
    }
  }
}

// ---------------- gate finalize: sigmoid(raw + bias) ----------------
__global__ __launch_bounds__(256) void k_gates_fin(const float* __restrict__ raw,
                                                   const float* __restrict__ bg,
                                                   const float* __restrict__ bb,
                                                   float* __restrict__ alpha,
                                                   float* __restrict__ beta) {
  int i = blockIdx.x * 256 + threadIdx.x;   // BT*16
  if (i >= BT * NH) return;
  int bt = i >> 4, h = i & 15;
  float ga = raw[(long)bt * 128 + h] + bg[h];
  float gb = raw[(long)bt * 128 + 16 + h] + bb[h];
  alpha[i] = 1.f / (1.f + __expf(-ga));
  beta[i]  = 1.f / (1.f + __expf(-gb));
}

// ---------------- L2-normalize q,k heads in-place (bf16) ----------------
__global__ __launch_bounds__(256) void k_l2norm(u16* __restrict__ qkv) {
  const int vid = blockIdx.x * 4 + (threadIdx.x >> 6);  // BT*2*16 vectors
  const int l = threadIdx.x & 63;
  const int h = vid & 15;
  const int s = (vid >> 4) & 1;     // 0=q, 1=k
  const long bt = vid >> 5;
  const long off = (bt * 3 + s) * 1024 + h * 64 + l;
  float f = bf2f(qkv[off]);
  float ss = f * f;
#pragma unroll
  for (int d = 1; d < 64; d <<= 1) ss += __shfl_xor(ss, d);
  float scale = 1.f / fmaxf(sqrtf(ss), 1e-12f);
  qkv[off] = f2bf(f * scale);
}

// ---------------- sequential gated-delta scan ----------------
// 64 (b,h) pairs x 8 row-groups = 512 blocks of 1 wave.
// Lane owns 8 S elements: row = rg*8 + (l>>3), cols c0..c0+7 with c0=(l&7)*8.
__global__ __launch_bounds__(64) void k_scan(const u16* __restrict__ qkv,
                                             const float* __restrict__ alpha,
                                             const float* __restrict__ beta,
                                             u16* __restrict__ ob) {
  const int blk = blockIdx.x;
  const int pair = blk >> 3, rg = blk & 7;
  const int b = pair >> 4, h = pair & 15;
  const int l = threadIdx.x;
  const int row = rg * 8 + (l >> 3);
  const int c0 = (l & 7) << 3;
  float S[8];
#pragma unroll
  for (int m = 0; m < 8; ++m) S[m] = 0.f;
  const long base0 = (long)b * NT * 3072 + h * 64;
  const long gbase0 = (long)b * NT * 16 + h;

  u16x8 kv, qv; u16 vb; float av, bv;
  {
    const long base = base0;
    kv = *(const u16x8*)&qkv[base + 1024 + c0];
    qv = *(const u16x8*)&qkv[base + c0];
    vb = qkv[base + 2048 + row];
    av = alpha[gbase0]; bv = beta[gbase0];
  }
  for (int t = 0; t < NT; ++t) {
    u16x8 nk, nq; u16 nvb = 0; float nav = 0.f, nbv = 0.f;
    if (t + 1 < NT) {
      const long base = base0 + (long)(t + 1) * 3072;
      nk = *(const u16x8*)&qkv[base + 1024 + c0];
      nq = *(const u16x8*)&qkv[base + c0];
      nvb = qkv[base + 2048 + row];
      nav = alpha[gbase0 + (long)(t + 1) * 16];
      nbv = beta[gbase0 + (long)(t + 1) * 16];
    }
    float kf[8], qf[8];
#pragma unroll
    for (int j = 0; j < 8; ++j) { kf[j] = bf2f(kv[j]); qf[j] = bf2f(qv[j]); }
    // Sk_i = sum_j S_ij k_j  (partial over my 8 cols, then reduce 8 lanes)
    float s0 = 0.f, s1 = 0.f;
#pragma unroll
    for (int j = 0; j < 4; ++j) { s0 += S[j] * kf[j]; s1 += S[4 + j] * kf[4 + j]; }
    float sk = s0 + s1;
    sk += __shfl_xor(sk, 1);
    sk += __shfl_xor(sk, 2);
    sk += __shfl_xor(sk, 4);
    const float vvv = bf2f(vb);
    const float u = bv * vvv - av * bv * sk;   // S_ij = av*S_ij + u*k_j
    float o0 = 0.f, o1 = 0.f;
#pragma unroll
    for (int j = 0; j < 4; ++j) {
      S[j]     = av * S[j]     + u * kf[j];     o0 += S[j]     * qf[j];
      S[4 + j] = av * S[4 + j] + u * kf[4 + j]; o1 += S[4 + j] * qf[4 + j];
    }
    float o = o0 + o1;
    o += __shfl_xor(o, 1);
    o += __shfl_xor(o, 2);
    o += __shfl_xor(o, 4);
    if ((l & 7) == 0)
      ob[(long)(b * NT + t) * 1024 + h * 64 + row] = f2bf(o);
    kv = nk; qv = nq; vb = nvb; av = nav; bv = nbv;
  }
}

extern "C" void kernel_launch(void* const* d_in, const int* in_sizes, int n_in,
                              void* d_out, int out_size, void* d_ws, size_t ws_size,
                              hipStream_t stream) {
  const float* x    = (const float*)d_in[0];   // 4*4096*1024
  const float* Wqkv = (const float*)d_in[1];   // 3072*1024
  const float* Wg   = (const float*)d_in[2];   // 16*1024
  const float* bg   = (const float*)d_in[3];   // 16
  const float* Wb   = (const float*)d_in[4];   // 16*1024
  const float* bb   = (const float*)d_in[5];   // 16
  const float* Wout = (const float*)d_in[6];   // 1024*1024
  float* out = (float*)d_out;

  char* ws = (char*)d_ws;
  u16* xb    = (u16*)ws;                               // 16384*1024
  u16* wqkvb = xb    + (long)BT * NDIM;                // 3072*1024
  u16* woutb = wqkvb + (long)3072 * 1024;              // 1024*1024
  u16* wgbb  = woutb + (long)1024 * 1024;              // 128*1024
  u16* qkvb  = wgbb  + (long)128 * 1024;               // 16384*3072
  u16* ob    = qkvb  + (long)BT * 3072;                // 16384*1024
  float* graw  = (float*)(ob + (long)BT * NDIM);       // 16384*128
  float* alpha = graw + (long)BT * 128;                // 16384*16
  float* beta  = alpha + (long)BT * NH;                // 16384*16

  // 1. converts
  k_f32_to_bf16<<<(BT * (long)NDIM / 4 + 255) / 256, 256, 0, stream>>>(x, xb, BT * (long)NDIM / 4);
  k_f32_to_bf16<<<(3072L * 1024 / 4 + 255) / 256, 256, 0, stream>>>(Wqkv, wqkvb, 3072L * 1024 / 4);
  k_f32_to_bf16<<<(1024L * 1024 / 4 + 255) / 256, 256, 0, stream>>>(Wout, woutb, 1024L * 1024 / 4);
  k_build_wgb<<<(128 * 1024) / 256, 256, 0, stream>>>(Wg, Wb, wgbb);

  // 2. qkv GEMM: (16384 x 3072) = xb @ wqkvb^T
  k_gemm_bt<u16><<<dim3(3072 / 128, BT / 128), 256, 0, stream>>>(xb, wqkvb, qkvb, BT, 3072, NDIM);

  // 3. gates GEMM (padded N=128) + finalize
  k_gemm_bt<float><<<dim3(1, BT / 128), 256, 0, stream>>>(xb, wgbb, graw, BT, 128, NDIM);
  k_gates_fin<<<(BT * NH + 255) / 256, 256, 0, stream>>>(graw, bg, bb, alpha, beta);

  // 4. l2 normalize q,k
  k_l2norm<<<(BT * 2 * NH) / 4, 256, 0, stream>>>(qkvb);

  // 5. sequential scan -> ob (bf16)
  k_scan<<<512, 64, 0, stream>>>(qkvb, alpha, beta, ob);

  // 6. out GEMM: out = ob @ woutb^T  (fp32 out)
  k_gemm_bt<float><<<dim3(NDIM / 128, BT / 128), 256, 0, stream>>>(ob, woutb, out, BT, NDIM, NDIM);
}

// Round 2
// 1393.445 us; speedup vs baseline: 1.9632x; 1.9632x over previous
//
#include <hip/hip_runtime.h>
#include <hip/hip_bf16.h>

// Problem constants
#define NB   4
#define NT   4096
#define BT   16384   // NB*NT
#define NDIM 1024
#define NH   16
#define NDH  64
#define CT   32      // scan chunk (time steps per LDS stage)
#define NC   (NT / CT)

using u16 = unsigned short;
typedef __bf16 bf16x8 __attribute__((ext_vector_type(8)));
typedef float f32x4 __attribute__((ext_vector_type(4)));
typedef unsigned short u16x8 __attribute__((ext_vector_type(8)));
typedef unsigned short u16x4 __attribute__((ext_vector_type(4)));

__device__ __forceinline__ float bf2f(u16 b) { return __uint_as_float(((unsigned)b) << 16); }
__device__ __forceinline__ u16 f2bf(float f) {
  return __builtin_bit_cast(u16, __float2bfloat16(f));
}

// ---------------- convert fp32 -> bf16 (vectorized) ----------------
__global__ __launch_bounds__(256) void k_f32_to_bf16(const float* __restrict__ in,
                                                     u16* __restrict__ out, long n4) {
  long i = (long)blockIdx.x * blockDim.x + threadIdx.x;
  if (i >= n4) return;
  float4 f = reinterpret_cast<const float4*>(in)[i];
  u16x4 o;
  o.x = f2bf(f.x); o.y = f2bf(f.y); o.z = f2bf(f.z); o.w = f2bf(f.w);
  reinterpret_cast<u16x4*>(out)[i] = o;
}

// ---------------- build padded gate weight matrix (128 x 1024 bf16) ----------------
__global__ __launch_bounds__(256) void k_build_wgb(const float* __restrict__ Wg,
                                                   const float* __restrict__ Wb,
                                                   u16* __restrict__ out) {
  int i = blockIdx.x * 256 + threadIdx.x;      // 128*1024 threads
  int row = i >> 10, col = i & 1023;
  float f = 0.f;
  if (row < 16)       f = Wg[row * 1024 + col];
  else if (row < 32)  f = Wb[(row - 16) * 1024 + col];
  out[i] = f2bf(f);
}

// ---------------- global_load_lds helpers ----------------
typedef unsigned int u32_as1 __attribute__((address_space(1)));
typedef unsigned int u32_as3 __attribute__((address_space(3)));
__device__ __forceinline__ void gload_lds16(const void* g, void* l) {
  __builtin_amdgcn_global_load_lds((const u32_as1*)g, (u32_as3*)l, 16, 0, 0);
}
__device__ __forceinline__ void gload_lds4(const void* g, void* l) {
  __builtin_amdgcn_global_load_lds((const u32_as1*)g, (u32_as3*)l, 4, 0, 0);
}

// ---------------- bf16 GEMM: C(MxN) = A(MxK) @ B(NxK)^T ----------------
template <typename OutT>
__global__ __launch_bounds__(256) void k_gemm_bt(const u16* __restrict__ A,
                                                 const u16* __restrict__ B,
                                                 OutT* __restrict__ C,
                                                 int M, int N, int K) {
  constexpr int BM = 128, BN = 128, BK = 32;
  __shared__ __align__(16) u16 As[BM * BK];
  __shared__ __align__(16) u16 Bs[BN * BK];
  const int tid = threadIdx.x;
  const int l = tid & 63, w = tid >> 6;
  const int tn = blockIdx.x, tm = blockIdx.y;
  const long a0 = (long)tm * BM * K;
  const long b0 = (long)tn * BN * K;
  const int srow = tid >> 2;
  const int scol = (tid & 3) << 3;
  const int wrow = (w >> 1) << 6;
  const int wcol = (w & 1) << 6;
  const int fr = l & 15, fq = l >> 4;

  f32x4 acc[4][4];
#pragma unroll
  for (int m = 0; m < 4; ++m)
#pragma unroll
    for (int n = 0; n < 4; ++n) acc[m][n] = f32x4{0.f, 0.f, 0.f, 0.f};

  for (int kk = 0; kk < K; kk += BK) {
    __syncthreads();
    const u16* gA = A + a0 + (long)srow * K + kk + scol;
    const u16* gB = B + b0 + (long)srow * K + kk + scol;
    gload_lds16(gA,               &As[(w * 16) * BK]);
    gload_lds16(gA + 64 * (long)K, &As[(64 + w * 16) * BK]);
    gload_lds16(gB,               &Bs[(w * 16) * BK]);
    gload_lds16(gB + 64 * (long)K, &Bs[(64 + w * 16) * BK]);
    __syncthreads();

    bf16x8 af[4], bfv[4];
#pragma unroll
    for (int m = 0; m < 4; ++m)
      af[m] = *(const bf16x8*)&As[(wrow + m * 16 + fr) * BK + (fq << 3)];
#pragma unroll
    for (int n = 0; n < 4; ++n)
      bfv[n] = *(const bf16x8*)&Bs[(wcol + n * 16 + fr) * BK + (fq << 3)];
#pragma unroll
    for (int m = 0; m < 4; ++m)
#pragma unroll
      for (int n = 0; n < 4; ++n)
        acc[m][n] = __builtin_amdgcn_mfma_f32_16x16x32_bf16(af[m], bfv[n], acc[m][n], 0, 0, 0);
  }

#pragma unroll
  for (int m = 0; m < 4; ++m) {
#pragma unroll
    for (int n = 0; n < 4; ++n) {
      const int r0 = tm * BM + wrow + m * 16 + fq * 4;
      const int c  = tn * BN + wcol + n * 16 + fr;
#pragma unroll
      for (int r = 0; r < 4; ++r) {
        float v = acc[m][n][r];
        long idx = (long)(r0 + r) * N + c;
        if constexpr (sizeof(OutT) == 2) C[idx] = f2bf(v);
        else                             C[idx] = v;
      }
    }
  }
}

// ---------------- gate finalize: sigmoid(raw + bias) ----------------
__global__ __launch_bounds__(256) void k_gates_fin(const float* __restrict__ raw,
                                                   const float* __restrict__ bg,
                                                   const float* __restrict__ bb,
                                                   float* __restrict__ alpha,
                                                   float* __restrict__ beta) {
  int i = blockIdx.x * 256 + threadIdx.x;   // BT*16
  if (i >= BT * NH) return;
  int bt = i >> 4, h = i & 15;
  float ga = raw[(long)bt * 128 + h] + bg[h];
  float gb = raw[(long)bt * 128 + 16 + h] + bb[h];
  alpha[i] = 1.f / (1.f + __expf(-ga));
  beta[i]  = 1.f / (1.f + __expf(-gb));
}

// ---------------- L2-normalize q,k heads in-place (bf16, vectorized) ----------------
// 8 lanes per head; each lane owns 8 contiguous elems (u16x8).
__global__ __launch_bounds__(256) void k_l2norm(u16* __restrict__ qkv) {
  const int vid = blockIdx.x * 32 + (threadIdx.x >> 3);   // head id over BT*2*16
  const int g = threadIdx.x & 7;
  const int h = vid & 15;
  const int s = (vid >> 4) & 1;     // 0=q, 1=k
  const long bt = vid >> 5;
  const long off = (bt * 3 + s) * 1024 + h * 64 + g * 8;
  u16x8 x = *(const u16x8*)&qkv[off];
  float f[8];
  float ss = 0.f;
#pragma unroll
  for (int e = 0; e < 8; ++e) { f[e] = bf2f(x[e]); ss += f[e] * f[e]; }
  ss += __shfl_xor(ss, 1);
  ss += __shfl_xor(ss, 2);
  ss += __shfl_xor(ss, 4);
  float sc = 1.f / fmaxf(sqrtf(ss), 1e-12f);
#pragma unroll
  for (int e = 0; e < 8; ++e) x[e] = f2bf(f[e] * sc);
  *(u16x8*)&qkv[off] = x;
}

// ---------------- meta precompute: (a, b, a*b, c_t = k_t . k_{t+1}) ----------------
// grid: 64 pairs * 64 t-chunks, 64 threads; lane handles t = tc*64 + l.
__global__ __launch_bounds__(64) void k_meta(const u16* __restrict__ qkv,
                                             const float* __restrict__ alpha,
                                             const float* __restrict__ beta,
                                             float4* __restrict__ meta) {
  const int blk = blockIdx.x;
  const int pair = blk >> 6, tc = blk & 63;
  const int b = pair >> 4, h = pair & 15;
  const int l = threadIdx.x;
  const int t = tc * 64 + l;
  const long kbase = (long)b * NT * 3072 + 1024 + h * 64;
  float c = 0.f;
  if (t + 1 < NT) {
    const u16x8* r0 = (const u16x8*)&qkv[kbase + (long)t * 3072];
    const u16x8* r1 = (const u16x8*)&qkv[kbase + (long)(t + 1) * 3072];
#pragma unroll
    for (int s8 = 0; s8 < 8; ++s8) {
      u16x8 xx = r0[s8], yy = r1[s8];
#pragma unroll
      for (int e = 0; e < 8; ++e) c += bf2f(xx[e]) * bf2f(yy[e]);
    }
  }
  const long gi = (long)(b * NT + t) * 16 + h;
  float a = alpha[gi];
  float bv = beta[gi];
  meta[(long)pair * NT + t] = make_float4(a, bv, a * bv, c);
}

// ---------------- sequential gated-delta scan (v2) ----------------
// 64 pairs x 16 row-groups = 1024 blocks of 1 wave (64 lanes).
// Block owns 4 rows of S (row = rg*4 + (l>>4)); lane owns 4 consecutive cols
// c0=(l&15)*4.  Inputs staged per 32-step chunk in double-buffered LDS via
// async global_load_lds (counted vmcnt(11), never drained in steady state).
// Dependency chain collapsed via: sk_t = a_{t-1}*d_t + u_{t-1}*c_{t-1}
// with d_t = S_{t-2}.k_t (computed one step early, shfl-reduce hidden) and
// c_t = k_t.k_{t+1} precomputed by k_meta.
__global__ __launch_bounds__(64) void k_scan2(const u16* __restrict__ qkv,
                                              const float4* __restrict__ meta,
                                              u16* __restrict__ ob) {
  __shared__ __align__(16) u16 kbuf[2][33 * 64];
  __shared__ __align__(16) u16 qbuf[2][32 * 64];
  __shared__ __align__(16) u16 vbuf[2][128];     // 32 steps * 4 rows
  __shared__ __align__(16) float4 mbuf[2][32];

  const int blk = blockIdx.x;
  const int pair = blk >> 4, rg = blk & 15;
  const int b = pair >> 4, h = pair & 15;
  const int l = threadIdx.x;
  const int rowl = l >> 4;            // 0..3
  const int c0 = (l & 15) << 2;       // 0..60
  const long base = (long)b * NT * 3072 + h * 64;      // q; +1024 k; +2048 v
  const long obase = (long)b * NT * 1024 + h * 64 + rg * 4 + rowl;

  auto stage = [&](int c, int bi) {
    const long t0 = (long)c * CT;
    // K rows t0..t0+32 (33 rows x 128B) : 5 passes (last predicated)
#pragma unroll
    for (int p = 0; p < 5; ++p) {
      int idx = p * 64 + l;
      if (idx < 264) {
        int row = idx >> 3, seg = idx & 7;
        long t = t0 + row; if (t > NT - 1) t = NT - 1;
        gload_lds16(&qkv[base + 1024 + t * 3072 + seg * 8], &kbuf[bi][p * 512]);
      }
    }
    // Q rows t0..t0+31 : 4 passes
#pragma unroll
    for (int p = 0; p < 4; ++p) {
      int idx = p * 64 + l;
      int row = idx >> 3, seg = idx & 7;
      gload_lds16(&qkv[base + (t0 + row) * 3072 + seg * 8], &qbuf[bi][p * 512]);
    }
    // V: 32 steps x 4 rows (8B/step) : lane -> (j = l>>1, p = l&1) 4B each
    { int j = l >> 1, p = l & 1;
      gload_lds4(&qkv[base + 2048 + (t0 + j) * 3072 + rg * 4 + p * 2], &vbuf[bi][0]); }
    // meta: 32 x float4
    if (l < 32)
      gload_lds16(&meta[(long)pair * NT + t0 + l], &mbuf[bi][0]);
  };

  stage(0, 0);
  asm volatile("s_waitcnt vmcnt(0)" ::: "memory");
  __builtin_amdgcn_sched_barrier(0);

  float S0 = 0.f, S1 = 0.f, S2 = 0.f, S3 = 0.f;
  float kf0, kf1, kf2, kf3;
  { u16x4 kx = *(const u16x4*)&kbuf[0][c0];
    kf0 = bf2f(kx[0]); kf1 = bf2f(kx[1]); kf2 = bf2f(kx[2]); kf3 = bf2f(kx[3]); }
  float u_p = 0.f, a_p = 0.f, c_p = 0.f, dsum = 0.f;

  for (int c = 0; c < NC; ++c) {
    const int bi = c & 1;
    if (c + 1 < NC) {
      stage(c + 1, bi ^ 1);
      asm volatile("s_waitcnt vmcnt(11)" ::: "memory");   // chunk c ready; c+1 in flight
    } else {
      asm volatile("s_waitcnt vmcnt(0)" ::: "memory");
    }
    __builtin_amdgcn_sched_barrier(0);
    const u16* kb = kbuf[bi];
    const u16* qb = qbuf[bi];
    const u16* vb = vbuf[bi];
    const float4* mb = mbuf[bi];
    const long tg = (long)c * CT;
#pragma unroll
    for (int j = 0; j < CT; ++j) {
      // d_{t+1} = S_{t-1} . k_{t+1}  (uses S BEFORE update; reduce hidden 1 step)
      u16x4 kx = *(const u16x4*)&kb[(j + 1) * 64 + c0];
      float kn0 = bf2f(kx[0]), kn1 = bf2f(kx[1]), kn2 = bf2f(kx[2]), kn3 = bf2f(kx[3]);
      float dp = S0 * kn0 + S1 * kn1 + S2 * kn2 + S3 * kn3;
      dp += __shfl_xor(dp, 1);
      dp += __shfl_xor(dp, 2);
      dp += __shfl_xor(dp, 4);
      dp += __shfl_xor(dp, 8);
      const float4 m = mb[j];
      const float vf = bf2f(vb[j * 4 + rowl]);
      const float sk = fmaf(u_p, c_p, a_p * dsum);      // S_{t-1}.k_t
      const float u = fmaf(-m.z, sk, m.y * vf);          // b*v - a*b*sk
      S0 = fmaf(m.x, S0, u * kf0);
      S1 = fmaf(m.x, S1, u * kf1);
      S2 = fmaf(m.x, S2, u * kf2);
      S3 = fmaf(m.x, S3, u * kf3);
      u16x4 qx = *(const u16x4*)&qb[j * 64 + c0];
      float o = S0 * bf2f(qx[0]) + S1 * bf2f(qx[1]) + S2 * bf2f(qx[2]) + S3 * bf2f(qx[3]);
      o += __shfl_xor(o, 1);
      o += __shfl_xor(o, 2);
      o += __shfl_xor(o, 4);
      o += __shfl_xor(o, 8);
      if ((l & 15) == 0) ob[obase + (tg + j) * 1024] = f2bf(o);
      kf0 = kn0; kf1 = kn1; kf2 = kn2; kf3 = kn3;
      u_p = u; a_p = m.x; c_p = m.w; dsum = dp;
    }
  }
}

extern "C" void kernel_launch(void* const* d_in, const int* in_sizes, int n_in,
                              void* d_out, int out_size, void* d_ws, size_t ws_size,
                              hipStream_t stream) {
  const float* x    = (const float*)d_in[0];
  const float* Wqkv = (const float*)d_in[1];
  const float* Wg   = (const float*)d_in[2];
  const float* bg   = (const float*)d_in[3];
  const float* Wb   = (const float*)d_in[4];
  const float* bb   = (const float*)d_in[5];
  const float* Wout = (const float*)d_in[6];
  float* out = (float*)d_out;

  char* ws = (char*)d_ws;
  u16* xb    = (u16*)ws;                               // 16384*1024
  u16* wqkvb = xb    + (long)BT * NDIM;                // 3072*1024
  u16* woutb = wqkvb + (long)3072 * 1024;              // 1024*1024
  u16* wgbb  = woutb + (long)1024 * 1024;              // 128*1024
  u16* qkvb  = wgbb  + (long)128 * 1024;               // 16384*3072
  u16* ob    = qkvb  + (long)BT * 3072;                // 16384*1024
  float* graw  = (float*)(ob + (long)BT * NDIM);       // 16384*128
  float* alpha = graw + (long)BT * 128;                // 16384*16
  float* beta  = alpha + (long)BT * NH;                // 16384*16
  float4* meta = (float4*)(beta + (long)BT * NH);      // 64*4096 float4

  // 1. converts
  k_f32_to_bf16<<<(BT * (long)NDIM / 4 + 255) / 256, 256, 0, stream>>>(x, xb, BT * (long)NDIM / 4);
  k_f32_to_bf16<<<(3072L * 1024 / 4 + 255) / 256, 256, 0, stream>>>(Wqkv, wqkvb, 3072L * 1024 / 4);
  k_f32_to_bf16<<<(1024L * 1024 / 4 + 255) / 256, 256, 0, stream>>>(Wout, woutb, 1024L * 1024 / 4);
  k_build_wgb<<<(128 * 1024) / 256, 256, 0, stream>>>(Wg, Wb, wgbb);

  // 2. qkv GEMM
  k_gemm_bt<u16><<<dim3(3072 / 128, BT / 128), 256, 0, stream>>>(xb, wqkvb, qkvb, BT, 3072, NDIM);

  // 3. gates GEMM + finalize
  k_gemm_bt<float><<<dim3(1, BT / 128), 256, 0, stream>>>(xb, wgbb, graw, BT, 128, NDIM);
  k_gates_fin<<<(BT * NH + 255) / 256, 256, 0, stream>>>(graw, bg, bb, alpha, beta);

  // 4. l2 normalize q,k
  k_l2norm<<<(BT * 2 * NH) / 32, 256, 0, stream>>>(qkvb);

  // 5. meta precompute (needs normalized k)
  k_meta<<<64 * 64, 64, 0, stream>>>(qkvb, alpha, beta, meta);

  // 6. scan v2
  k_scan2<<<1024, 64, 0, stream>>>(qkvb, meta, ob);

  // 7. out GEMM
  k_gemm_bt<float><<<dim3(NDIM / 128, BT / 128), 256, 0, stream>>>(ob, woutb, out, BT, NDIM, NDIM);
}

// Round 4
// 754.532 us; speedup vs baseline: 3.6255x; 1.8468x over previous
//
#include <hip/hip_runtime.h>
#include <hip/hip_bf16.h>

// Problem constants
#define NB   4
#define NT   4096
#define BT   16384   // NB*NT
#define NDIM 1024
#define NH   16
#define NDH  64
#define CC   64              // chunk size (time steps)
#define NCH  (NT / CC)       // 64 chunks per pair
#define NPAIR 64             // B*H
#define NU   (NPAIR * NCH)   // 4096 units

using u16 = unsigned short;
typedef __bf16 bf16x8 __attribute__((ext_vector_type(8)));
typedef float f32x4 __attribute__((ext_vector_type(4)));
typedef unsigned short u16x8 __attribute__((ext_vector_type(8)));
typedef unsigned short u16x4 __attribute__((ext_vector_type(4)));

__device__ __forceinline__ float bf2f(u16 b) { return __uint_as_float(((unsigned)b) << 16); }
__device__ __forceinline__ u16 f2bf(float f) {
  return __builtin_bit_cast(u16, __float2bfloat16(f));
}
// LDS row swizzle (u16-element index, 8-elem granular): breaks stride-128B bank conflicts
__device__ __forceinline__ int swz(int row, int e) { return e ^ ((row & 7) << 3); }

// ---------------- convert fp32 -> bf16 (vectorized) ----------------
__global__ __launch_bounds__(256) void k_f32_to_bf16(const float* __restrict__ in,
                                                     u16* __restrict__ out, long n4) {
  long i = (long)blockIdx.x * blockDim.x + threadIdx.x;
  if (i >= n4) return;
  float4 f = reinterpret_cast<const float4*>(in)[i];
  u16x4 o;
  o.x = f2bf(f.x); o.y = f2bf(f.y); o.z = f2bf(f.z); o.w = f2bf(f.w);
  reinterpret_cast<u16x4*>(out)[i] = o;
}

// ---------------- build padded gate weight matrix (128 x 1024 bf16) ----------------
__global__ __launch_bounds__(256) void k_build_wgb(const float* __restrict__ Wg,
                                                   const float* __restrict__ Wb,
                                                   u16* __restrict__ out) {
  int i = blockIdx.x * 256 + threadIdx.x;      // 128*1024 threads
  int row = i >> 10, col = i & 1023;
  float f = 0.f;
  if (row < 16)       f = Wg[row * 1024 + col];
  else if (row < 32)  f = Wb[(row - 16) * 1024 + col];
  out[i] = f2bf(f);
}

// ---------------- global_load_lds helper ----------------
typedef unsigned int u32_as1 __attribute__((address_space(1)));
typedef unsigned int u32_as3 __attribute__((address_space(3)));
__device__ __forceinline__ void gload_lds16(const void* g, void* l) {
  __builtin_amdgcn_global_load_lds((const u32_as1*)g, (u32_as3*)l, 16, 0, 0);
}

// ---------------- bf16 GEMM: C(MxN) = A(MxK) @ B(NxK)^T ----------------
template <typename OutT>
__global__ __launch_bounds__(256) void k_gemm_bt(const u16* __restrict__ A,
                                                 const u16* __restrict__ B,
                                                 OutT* __restrict__ C,
                                                 int M, int N, int K) {
  constexpr int BM = 128, BN = 128, BK = 32;
  __shared__ __align__(16) u16 As[BM * BK];
  __shared__ __align__(16) u16 Bs[BN * BK];
  const int tid = threadIdx.x;
  const int l = tid & 63, w = tid >> 6;
  const int tn = blockIdx.x, tm = blockIdx.y;
  const long a0 = (long)tm * BM * K;
  const long b0 = (long)tn * BN * K;
  const int srow = tid >> 2;
  const int scol = (tid & 3) << 3;
  const int wrow = (w >> 1) << 6;
  const int wcol = (w & 1) << 6;
  const int fr = l & 15, fq = l >> 4;

  f32x4 acc[4][4];
#pragma unroll
  for (int m = 0; m < 4; ++m)
#pragma unroll
    for (int n = 0; n < 4; ++n) acc[m][n] = f32x4{0.f, 0.f, 0.f, 0.f};

  for (int kk = 0; kk < K; kk += BK) {
    __syncthreads();
    const u16* gA = A + a0 + (long)srow * K + kk + scol;
    const u16* gB = B + b0 + (long)srow * K + kk + scol;
    gload_lds16(gA,                &As[(w * 16) * BK]);
    gload_lds16(gA + 64 * (long)K, &As[(64 + w * 16) * BK]);
    gload_lds16(gB,                &Bs[(w * 16) * BK]);
    gload_lds16(gB + 64 * (long)K, &Bs[(64 + w * 16) * BK]);
    __syncthreads();

    bf16x8 af[4], bfv[4];
#pragma unroll
    for (int m = 0; m < 4; ++m)
      af[m] = *(const bf16x8*)&As[(wrow + m * 16 + fr) * BK + (fq << 3)];
#pragma unroll
    for (int n = 0; n < 4; ++n)
      bfv[n] = *(const bf16x8*)&Bs[(wcol + n * 16 + fr) * BK + (fq << 3)];
#pragma unroll
    for (int m = 0; m < 4; ++m)
#pragma unroll
      for (int n = 0; n < 4; ++n)
        acc[m][n] = __builtin_amdgcn_mfma_f32_16x16x32_bf16(af[m], bfv[n], acc[m][n], 0, 0, 0);
  }

#pragma unroll
  for (int m = 0; m < 4; ++m) {
#pragma unroll
    for (int n = 0; n < 4; ++n) {
      const int r0 = tm * BM + wrow + m * 16 + fq * 4;
      const int c  = tn * BN + wcol + n * 16 + fr;
#pragma unroll
      for (int r = 0; r < 4; ++r) {
        float v = acc[m][n][r];
        long idx = (long)(r0 + r) * N + c;
        if constexpr (sizeof(OutT) == 2) C[idx] = f2bf(v);
        else                             C[idx] = v;
      }
    }
  }
}

// ---------------- gate finalize: sigmoid(raw + bias) ----------------
__global__ __launch_bounds__(256) void k_gates_fin(const float* __restrict__ raw,
                                                   const float* __restrict__ bg,
                                                   const float* __restrict__ bb,
                                                   float* __restrict__ alpha,
                                                   float* __restrict__ beta) {
  int i = blockIdx.x * 256 + threadIdx.x;   // BT*16
  if (i >= BT * NH) return;
  int bt = i >> 4, h = i & 15;
  float ga = raw[(long)bt * 128 + h] + bg[h];
  float gb = raw[(long)bt * 128 + 16 + h] + bb[h];
  alpha[i] = 1.f / (1.f + __expf(-ga));
  beta[i]  = 1.f / (1.f + __expf(-gb));
}

// ---------------- L2-normalize q,k heads in-place (bf16, vectorized) ----------------
__global__ __launch_bounds__(256) void k_l2norm(u16* __restrict__ qkv) {
  const int vid = blockIdx.x * 32 + (threadIdx.x >> 3);   // head id over BT*2*16
  const int g = threadIdx.x & 7;
  const int h = vid & 15;
  const int s = (vid >> 4) & 1;     // 0=q, 1=k
  const long bt = vid >> 5;
  const long off = (bt * 3 + s) * 1024 + h * 64 + g * 8;
  u16x8 x = *(const u16x8*)&qkv[off];
  float f[8];
  float ss = 0.f;
#pragma unroll
  for (int e = 0; e < 8; ++e) { f[e] = bf2f(x[e]); ss += f[e] * f[e]; }
  ss += __shfl_xor(ss, 1);
  ss += __shfl_xor(ss, 2);
  ss += __shfl_xor(ss, 4);
  float sc = 1.f / fmaxf(sqrtf(ss), 1e-12f);
#pragma unroll
  for (int e = 0; e < 8; ++e) x[e] = f2bf(f[e] * sc);
  *(u16x8*)&qkv[off] = x;
}

// ================= chunked WY scan, in-place storage =================
// Recurrence: S_t = a_t S_{t-1} + w_t k_t^T,  w_t = b_t (v_t - a_t S_{t-1} k_t)
// Per chunk (t local 0..63, A_t = prod_{r<=t} a_r = 2^{c_t}):
//   (I+L)[Wv|Tw] = [diag(b)V | diag(bA)K],  L[t,s] = b_t 2^{c_t-c_s}(k_s.k_t), s<t
//   Mq[t,s] = 2^{c_t-c_s}(k_s.q_t) (s<=t);  Kd[t,:] = 2^{c_63-c_t} k_t
//   O      = (Mq Wv)          + (diag(A)Q - Mq Tw) S0^T  =  O_intra + Qeff S0^T
//   S_end  = A63 S0 + S0 G + U,   G = -(Kd^T Tw),  U = Wv^T Kd
// k_prep (4096 parallel units): computes O_intra -> ob, and writes
//   Qeff -> q-slot, G -> k-slot, U -> v-slot of its OWN chunk in qkvb (slots
//   dead after LDS staging; no extra workspace).
// k_seq (64 blocks, 64 sequential chunks): ob += Qeff S^T ; S = A63 S + S G + U.

__global__ __launch_bounds__(256) void k_prep(u16* __restrict__ qkv,
                                              const float* __restrict__ alpha,
                                              const float* __restrict__ beta,
                                              float* __restrict__ A63G,
                                              u16* __restrict__ ob) {
  __shared__ __align__(16) u16 Ks[64 * 64], Qs[64 * 64], Vs[64 * 64];
  __shared__ __align__(16) u16 MqS[64 * 64], TwT[64 * 64], WvT[64 * 64], KdT[64 * 64];
  __shared__ float Ls[64 * 64];
  __shared__ float cvec[64], Avec[64], bvec[64];

  const int unit = blockIdx.x;
  const int pair = unit >> 6, ch = unit & 63;
  const int b = pair >> 4, h = pair & 15;
  const int tid = threadIdx.x, l = tid & 63, w = tid >> 6;
  const int fr = l & 15, fq = l >> 4;
  const long t0 = (long)b * NT + (long)ch * CC;   // global bt of chunk start

  // ---- stage q,k,v (64x64 bf16 each) into swizzled LDS ----
#pragma unroll
  for (int p = 0; p < 2; ++p) {
    int idx = p * 256 + tid;            // 0..511 = 64 rows x 8 segs
    int row = idx >> 3, seg = (idx & 7) * 8;
    long g = (t0 + row) * 3072 + h * 64 + seg;
    u16x8 qv = *(const u16x8*)&qkv[g];
    u16x8 kv = *(const u16x8*)&qkv[g + 1024];
    u16x8 vv = *(const u16x8*)&qkv[g + 2048];
    int o = row * 64 + swz(row, seg);
    *(u16x8*)&Qs[o] = qv; *(u16x8*)&Ks[o] = kv; *(u16x8*)&Vs[o] = vv;
  }
  __syncthreads();

  // ---- wave 0: log2-cumsum of a ----
  if (w == 0) {
    float av = alpha[(t0 + l) * 16 + h];
    float bv = beta[(t0 + l) * 16 + h];
    float cl = __log2f(av);
#pragma unroll
    for (int d = 1; d < 64; d <<= 1) {
      float up = __shfl_up(cl, d);
      if (l >= d) cl += up;
    }
    float A = exp2f(cl);
    cvec[l] = cl; Avec[l] = A; bvec[l] = bv;
    if (l == 63) A63G[unit] = A;
  }
  __syncthreads();

  // ---- GEMMs: KK^T and QK^T (64x64, K=64); wave w owns t-rows [16w,16w+16) ----
  f32x4 akk[4], aqk[4];
#pragma unroll
  for (int n = 0; n < 4; ++n) { akk[n] = f32x4{0, 0, 0, 0}; aqk[n] = f32x4{0, 0, 0, 0}; }
  {
    const int ar = w * 16 + fr;
    bf16x8 afK[2], afQ[2];
#pragma unroll
    for (int kk = 0; kk < 2; ++kk) {
      afK[kk] = __builtin_bit_cast(bf16x8, *(const u16x8*)&Ks[ar * 64 + swz(ar, kk * 32 + fq * 8)]);
      afQ[kk] = __builtin_bit_cast(bf16x8, *(const u16x8*)&Qs[ar * 64 + swz(ar, kk * 32 + fq * 8)]);
    }
#pragma unroll
    for (int n = 0; n < 4; ++n) {
      const int br = n * 16 + fr;
#pragma unroll
      for (int kk = 0; kk < 2; ++kk) {
        bf16x8 bk = __builtin_bit_cast(bf16x8, *(const u16x8*)&Ks[br * 64 + swz(br, kk * 32 + fq * 8)]);
        akk[n] = __builtin_amdgcn_mfma_f32_16x16x32_bf16(afK[kk], bk, akk[n], 0, 0, 0);
        aqk[n] = __builtin_amdgcn_mfma_f32_16x16x32_bf16(afQ[kk], bk, aqk[n], 0, 0, 0);
      }
    }
  }
  // ---- epilogue: L (fp32 LDS, s<t) and Mq (bf16 LDS, s<=t) ----
#pragma unroll
  for (int n = 0; n < 4; ++n) {
#pragma unroll
    for (int r = 0; r < 4; ++r) {
      const int t = w * 16 + fq * 4 + r;
      const int s = n * 16 + fr;
      const float e = exp2f(cvec[t] - cvec[s]);
      Ls[t * 64 + s] = (s < t) ? bvec[t] * e * akk[n][r] : 0.f;
      MqS[t * 64 + swz(t, s)] = (s <= t) ? f2bf(e * aqk[n][r]) : (u16)0;
    }
  }
  __syncthreads();

  // ---- waves 0-1: forward substitution (128 RHS cols in registers) ----
  if (tid < 128) {
    float R[64];
    const int col = tid;
#pragma unroll
    for (int t = 0; t < 64; ++t) {
      u16 m; float sc2;
      if (col < 64) { m = Vs[t * 64 + swz(t, col)];      sc2 = bvec[t]; }
      else          { m = Ks[t * 64 + swz(t, col - 64)]; sc2 = bvec[t] * Avec[t]; }
      R[t] = bf2f(m) * sc2;
    }
#pragma unroll
    for (int t = 1; t < 64; ++t) {
      float acc = 0.f;
      const float* Lr = &Ls[t * 64];
#pragma unroll
      for (int s4 = 0; s4 + 4 <= t; s4 += 4) {
        float4 lv = *(const float4*)&Lr[s4];
        acc += lv.x * R[s4] + lv.y * R[s4 + 1] + lv.z * R[s4 + 2] + lv.w * R[s4 + 3];
      }
#pragma unroll
      for (int s = t & ~3; s < t; ++s) acc += Lr[s] * R[s];
      R[t] -= acc;
    }
    if (col < 64) {
      // column col of Wv = row col of WvT
#pragma unroll
      for (int k8 = 0; k8 < 8; ++k8) {
        u16x8 o;
#pragma unroll
        for (int e = 0; e < 8; ++e) o[e] = f2bf(R[k8 * 8 + e]);
        *(u16x8*)&WvT[col * 64 + swz(col, k8 * 8)] = o;
      }
    } else {
      const int j = col - 64;   // column j of Tw = row j of TwT
#pragma unroll
      for (int k8 = 0; k8 < 8; ++k8) {
        u16x8 o;
#pragma unroll
        for (int e = 0; e < 8; ++e) o[e] = f2bf(R[k8 * 8 + e]);
        *(u16x8*)&TwT[j * 64 + swz(j, k8 * 8)] = o;
      }
    }
  } else {
    // ---- waves 2-3: KdT[j][t] = 2^(c63-c_t) K[t][j] ----
    const int tid2 = tid - 128;
    const int j = tid2 >> 1, th = (tid2 & 1) * 32;
    const float c63 = cvec[63];
#pragma unroll
    for (int k8 = 0; k8 < 4; ++k8) {
      u16x8 o;
#pragma unroll
      for (int e = 0; e < 8; ++e) {
        const int t = th + k8 * 8 + e;
        o[e] = f2bf(exp2f(c63 - cvec[t]) * bf2f(Ks[t * 64 + swz(t, j)]));
      }
      *(u16x8*)&KdT[j * 64 + swz(j, th + k8 * 8)] = o;
    }
  }
  __syncthreads();

  // ---- final 4 GEMMs (each 64x64, K=64): G, U, MqTw, MqWv ----
  f32x4 aG[4], aU[4], aQe[4], aOi[4];
#pragma unroll
  for (int n = 0; n < 4; ++n) {
    aG[n] = f32x4{0, 0, 0, 0}; aU[n] = f32x4{0, 0, 0, 0};
    aQe[n] = f32x4{0, 0, 0, 0}; aOi[n] = f32x4{0, 0, 0, 0};
  }
  {
    const int ar = w * 16 + fr;
    bf16x8 aKd[2], aWv[2], aMq[2];
#pragma unroll
    for (int kk = 0; kk < 2; ++kk) {
      aKd[kk] = __builtin_bit_cast(bf16x8, *(const u16x8*)&KdT[ar * 64 + swz(ar, kk * 32 + fq * 8)]);
      aWv[kk] = __builtin_bit_cast(bf16x8, *(const u16x8*)&WvT[ar * 64 + swz(ar, kk * 32 + fq * 8)]);
      aMq[kk] = __builtin_bit_cast(bf16x8, *(const u16x8*)&MqS[ar * 64 + swz(ar, kk * 32 + fq * 8)]);
    }
#pragma unroll
    for (int n = 0; n < 4; ++n) {
      const int br = n * 16 + fr;
#pragma unroll
      for (int kk = 0; kk < 2; ++kk) {
        bf16x8 bTw = __builtin_bit_cast(bf16x8, *(const u16x8*)&TwT[br * 64 + swz(br, kk * 32 + fq * 8)]);
        bf16x8 bKd = __builtin_bit_cast(bf16x8, *(const u16x8*)&KdT[br * 64 + swz(br, kk * 32 + fq * 8)]);
        bf16x8 bWv = __builtin_bit_cast(bf16x8, *(const u16x8*)&WvT[br * 64 + swz(br, kk * 32 + fq * 8)]);
        aG[n]  = __builtin_amdgcn_mfma_f32_16x16x32_bf16(aKd[kk], bTw, aG[n], 0, 0, 0);  // (Kd^T Tw)
        aU[n]  = __builtin_amdgcn_mfma_f32_16x16x32_bf16(aWv[kk], bKd, aU[n], 0, 0, 0);  // Wv^T Kd
        aQe[n] = __builtin_amdgcn_mfma_f32_16x16x32_bf16(aMq[kk], bTw, aQe[n], 0, 0, 0); // Mq Tw
        aOi[n] = __builtin_amdgcn_mfma_f32_16x16x32_bf16(aMq[kk], bWv, aOi[n], 0, 0, 0); // Mq Wv
      }
    }
  }
  // ---- epilogues: write in-place into this chunk's qkv slots + ob ----
#pragma unroll
  for (int n = 0; n < 4; ++n) {
#pragma unroll
    for (int r = 0; r < 4; ++r) {
      const int i = w * 16 + fq * 4 + r;   // row index (t for Qe/Oi, j for G, d for U)
      const int cn = n * 16 + fr;          // col index
      const long grow = (t0 + i) * 3072 + h * 64 + cn;
      // Qeff[t][j] = A_t Q[t][j] - (Mq Tw)[t][j]  -> q-slot
      const float qorig = bf2f(Qs[i * 64 + swz(i, cn)]);
      qkv[grow] = f2bf(Avec[i] * qorig - aQe[n][r]);
      // G[j][j'] = -(Kd^T Tw)[j][j']              -> k-slot
      qkv[grow + 1024] = f2bf(-aG[n][r]);
      // U[d][j]                                    -> v-slot
      qkv[grow + 2048] = f2bf(aU[n][r]);
      // O_intra[t][d]                              -> ob
      ob[(t0 + i) * 1024 + h * 64 + cn] = f2bf(aOi[n][r]);
    }
  }
}

// ---------------- sequential chunk recurrence ----------------
// 64 blocks (one per pair) x 256 threads; 64 sequential chunk steps.
// S[d][j] fp32 in accumulators; bf16 copy Sb in LDS for MFMA operands.
__global__ __launch_bounds__(256) void k_seq(const u16* __restrict__ qkv,
                                             const float* __restrict__ A63G,
                                             u16* __restrict__ ob) {
  __shared__ __align__(16) u16 Sb[64 * 64];
  const int pair = blockIdx.x;
  const int b = pair >> 4, h = pair & 15;
  const int tid = threadIdx.x, l = tid & 63, w = tid >> 6;
  const int fr = l & 15, fq = l >> 4;

  for (int i = tid; i < 4096; i += 256) Sb[i] = 0;
  f32x4 sacc[4];
#pragma unroll
  for (int n = 0; n < 4; ++n) sacc[n] = f32x4{0, 0, 0, 0};
  __syncthreads();

  for (int c = 0; c < NCH; ++c) {
    const long tg = (long)b * NT + (long)c * CC;
    const int ar = w * 16 + fr;

    // ---- O_cross[t][d] = sum_j Qeff[t][j] S[d][j] ----
    bf16x8 aq[2];
#pragma unroll
    for (int kk = 0; kk < 2; ++kk)
      aq[kk] = __builtin_bit_cast(bf16x8, *(const u16x8*)&qkv[(tg + ar) * 3072 + h * 64 + kk * 32 + fq * 8]);
    f32x4 ao[4];
#pragma unroll
    for (int n = 0; n < 4; ++n) ao[n] = f32x4{0, 0, 0, 0};
#pragma unroll
    for (int n = 0; n < 4; ++n) {
      const int br = n * 16 + fr;
#pragma unroll
      for (int kk = 0; kk < 2; ++kk) {
        bf16x8 sb = __builtin_bit_cast(bf16x8, *(const u16x8*)&Sb[br * 64 + swz(br, kk * 32 + fq * 8)]);
        ao[n] = __builtin_amdgcn_mfma_f32_16x16x32_bf16(aq[kk], sb, ao[n], 0, 0, 0);
      }
    }
    // ---- S update: sacc[d][j] = A63*sacc + sum_j' S[d][j'] G[j][j'] (+U later) ----
    bf16x8 as_[2];
#pragma unroll
    for (int kk = 0; kk < 2; ++kk)
      as_[kk] = __builtin_bit_cast(bf16x8, *(const u16x8*)&Sb[ar * 64 + swz(ar, kk * 32 + fq * 8)]);
    const float A63 = A63G[pair * 64 + c];
#pragma unroll
    for (int n = 0; n < 4; ++n) {
#pragma unroll
      for (int r = 0; r < 4; ++r) sacc[n][r] *= A63;
      const int br = n * 16 + fr;
#pragma unroll
      for (int kk = 0; kk < 2; ++kk) {
        bf16x8 g = __builtin_bit_cast(bf16x8, *(const u16x8*)&qkv[(tg + br) * 3072 + 1024 + h * 64 + kk * 32 + fq * 8]);
        sacc[n] = __builtin_amdgcn_mfma_f32_16x16x32_bf16(as_[kk], g, sacc[n], 0, 0, 0);
      }
    }
    // ---- +U, and ob += O_cross ----
#pragma unroll
    for (int n = 0; n < 4; ++n) {
#pragma unroll
      for (int r = 0; r < 4; ++r) {
        const int i = w * 16 + fq * 4 + r;   // t for ob, d for sacc
        const int cn = n * 16 + fr;          // d for ob, j for sacc
        const long oidx = (tg + i) * 1024 + h * 64 + cn;
        ob[oidx] = f2bf(bf2f(ob[oidx]) + ao[n][r]);
        sacc[n][r] += bf2f(qkv[(tg + i) * 3072 + 2048 + h * 64 + cn]);
      }
    }
    __syncthreads();   // all Sb reads done
#pragma unroll
    for (int n = 0; n < 4; ++n)
#pragma unroll
      for (int r = 0; r < 4; ++r) {
        const int d = w * 16 + fq * 4 + r, j = n * 16 + fr;
        Sb[d * 64 + swz(d, j)] = f2bf(sacc[n][r]);
      }
    __syncthreads();   // Sb ready for next chunk
  }
}

extern "C" void kernel_launch(void* const* d_in, const int* in_sizes, int n_in,
                              void* d_out, int out_size, void* d_ws, size_t ws_size,
                              hipStream_t stream) {
  const float* x    = (const float*)d_in[0];
  const float* Wqkv = (const float*)d_in[1];
  const float* Wg   = (const float*)d_in[2];
  const float* bg   = (const float*)d_in[3];
  const float* Wb   = (const float*)d_in[4];
  const float* bb   = (const float*)d_in[5];
  const float* Wout = (const float*)d_in[6];
  float* out = (float*)d_out;

  char* ws = (char*)d_ws;
  u16* xb    = (u16*)ws;                               // 16384*1024   (32MB)
  u16* wqkvb = xb    + (long)BT * NDIM;                // 3072*1024    (6MB)
  u16* woutb = wqkvb + (long)3072 * 1024;              // 1024*1024    (2MB)
  u16* wgbb  = woutb + (long)1024 * 1024;              // 128*1024
  u16* qkvb  = wgbb  + (long)128 * 1024;               // 16384*3072   (96MB)
  u16* ob    = qkvb  + (long)BT * 3072;                // 16384*1024   (32MB)
  float* graw  = (float*)(ob + (long)BT * NDIM);       // 16384*128    (8MB)
  float* alpha = graw + (long)BT * 128;                // 16384*16     (1MB)
  float* beta  = alpha + (long)BT * NH;                // 16384*16     (1MB)
  float* A63G  = graw;   // reuse: graw dead after k_gates_fin (needs 16KB)
  // peak ws usage: 178.25MB (< 182.25MB proven in R2)

  // 1. converts
  k_f32_to_bf16<<<(BT * (long)NDIM / 4 + 255) / 256, 256, 0, stream>>>(x, xb, BT * (long)NDIM / 4);
  k_f32_to_bf16<<<(3072L * 1024 / 4 + 255) / 256, 256, 0, stream>>>(Wqkv, wqkvb, 3072L * 1024 / 4);
  k_f32_to_bf16<<<(1024L * 1024 / 4 + 255) / 256, 256, 0, stream>>>(Wout, woutb, 1024L * 1024 / 4);
  k_build_wgb<<<(128 * 1024) / 256, 256, 0, stream>>>(Wg, Wb, wgbb);

  // 2. qkv GEMM
  k_gemm_bt<u16><<<dim3(3072 / 128, BT / 128), 256, 0, stream>>>(xb, wqkvb, qkvb, BT, 3072, NDIM);

  // 3. gates GEMM + finalize
  k_gemm_bt<float><<<dim3(1, BT / 128), 256, 0, stream>>>(xb, wgbb, graw, BT, 128, NDIM);
  k_gates_fin<<<(BT * NH + 255) / 256, 256, 0, stream>>>(graw, bg, bb, alpha, beta);

  // 4. l2 normalize q,k
  k_l2norm<<<(BT * 2 * NH) / 32, 256, 0, stream>>>(qkvb);

  // 5. chunked WY: parallel precompute (in-place outputs) + sequential chunk GEMMs
  k_prep<<<NU, 256, 0, stream>>>(qkvb, alpha, beta, A63G, ob);
  k_seq<<<NPAIR, 256, 0, stream>>>(qkvb, A63G, ob);

  // 6. out GEMM
  k_gemm_bt<float><<<dim3(NDIM / 128, BT / 128), 256, 0, stream>>>(ob, woutb, out, BT, NDIM, NDIM);
}

// Round 5
// 486.509 us; speedup vs baseline: 5.6228x; 1.5509x over previous
//
#include <hip/hip_runtime.h>
#include <hip/hip_bf16.h>

// Problem constants
#define NB   4
#define NT   4096
#define BT   16384   // NB*NT
#define NDIM 1024
#define NH   16
#define NDH  64
#define CC   64              // chunk size (time steps)
#define NCH  (NT / CC)       // 64 chunks per pair
#define NPAIR 64             // B*H
#define NU   (NPAIR * NCH)   // 4096 units
#define DBS  24              // Db row stride (u16 elems), padded for banks

using u16 = unsigned short;
typedef __bf16 bf16x8 __attribute__((ext_vector_type(8)));
typedef float f32x4 __attribute__((ext_vector_type(4)));
typedef unsigned short u16x8 __attribute__((ext_vector_type(8)));
typedef unsigned short u16x4 __attribute__((ext_vector_type(4)));

__device__ __forceinline__ float bf2f(u16 b) { return __uint_as_float(((unsigned)b) << 16); }
__device__ __forceinline__ u16 f2bf(float f) {
  return __builtin_bit_cast(u16, __float2bfloat16(f));
}
// LDS row swizzle (u16-element index, 8-elem granular): breaks stride-128B bank conflicts
__device__ __forceinline__ int swz(int row, int e) { return e ^ ((row & 7) << 3); }
__device__ __forceinline__ bf16x8 zfrag() {
  u16x8 z = {0, 0, 0, 0, 0, 0, 0, 0};
  return __builtin_bit_cast(bf16x8, z);
}

// ---------------- convert fp32 -> bf16 (vectorized) ----------------
__global__ __launch_bounds__(256) void k_f32_to_bf16(const float* __restrict__ in,
                                                     u16* __restrict__ out, long n4) {
  long i = (long)blockIdx.x * blockDim.x + threadIdx.x;
  if (i >= n4) return;
  float4 f = reinterpret_cast<const float4*>(in)[i];
  u16x4 o;
  o.x = f2bf(f.x); o.y = f2bf(f.y); o.z = f2bf(f.z); o.w = f2bf(f.w);
  reinterpret_cast<u16x4*>(out)[i] = o;
}

// ---------------- build padded gate weight matrix (128 x 1024 bf16) ----------------
__global__ __launch_bounds__(256) void k_build_wgb(const float* __restrict__ Wg,
                                                   const float* __restrict__ Wb,
                                                   u16* __restrict__ out) {
  int i = blockIdx.x * 256 + threadIdx.x;
  int row = i >> 10, col = i & 1023;
  float f = 0.f;
  if (row < 16)       f = Wg[row * 1024 + col];
  else if (row < 32)  f = Wb[(row - 16) * 1024 + col];
  out[i] = f2bf(f);
}

// ---------------- global_load_lds helper ----------------
typedef unsigned int u32_as1 __attribute__((address_space(1)));
typedef unsigned int u32_as3 __attribute__((address_space(3)));
__device__ __forceinline__ void gload_lds16(const void* g, void* l) {
  __builtin_amdgcn_global_load_lds((const u32_as1*)g, (u32_as3*)l, 16, 0, 0);
}

// ---------------- bf16 GEMM: C(MxN) = A(MxK) @ B(NxK)^T ----------------
template <typename OutT>
__global__ __launch_bounds__(256) void k_gemm_bt(const u16* __restrict__ A,
                                                 const u16* __restrict__ B,
                                                 OutT* __restrict__ C,
                                                 int M, int N, int K) {
  constexpr int BM = 128, BN = 128, BK = 32;
  __shared__ __align__(16) u16 As[BM * BK];
  __shared__ __align__(16) u16 Bs[BN * BK];
  const int tid = threadIdx.x;
  const int l = tid & 63, w = tid >> 6;
  const int tn = blockIdx.x, tm = blockIdx.y;
  const long a0 = (long)tm * BM * K;
  const long b0 = (long)tn * BN * K;
  const int srow = tid >> 2;
  const int scol = (tid & 3) << 3;
  const int wrow = (w >> 1) << 6;
  const int wcol = (w & 1) << 6;
  const int fr = l & 15, fq = l >> 4;

  f32x4 acc[4][4];
#pragma unroll
  for (int m = 0; m < 4; ++m)
#pragma unroll
    for (int n = 0; n < 4; ++n) acc[m][n] = f32x4{0.f, 0.f, 0.f, 0.f};

  for (int kk = 0; kk < K; kk += BK) {
    __syncthreads();
    const u16* gA = A + a0 + (long)srow * K + kk + scol;
    const u16* gB = B + b0 + (long)srow * K + kk + scol;
    gload_lds16(gA,                &As[(w * 16) * BK]);
    gload_lds16(gA + 64 * (long)K, &As[(64 + w * 16) * BK]);
    gload_lds16(gB,                &Bs[(w * 16) * BK]);
    gload_lds16(gB + 64 * (long)K, &Bs[(64 + w * 16) * BK]);
    __syncthreads();

    bf16x8 af[4], bfv[4];
#pragma unroll
    for (int m = 0; m < 4; ++m)
      af[m] = *(const bf16x8*)&As[(wrow + m * 16 + fr) * BK + (fq << 3)];
#pragma unroll
    for (int n = 0; n < 4; ++n)
      bfv[n] = *(const bf16x8*)&Bs[(wcol + n * 16 + fr) * BK + (fq << 3)];
#pragma unroll
    for (int m = 0; m < 4; ++m)
#pragma unroll
      for (int n = 0; n < 4; ++n)
        acc[m][n] = __builtin_amdgcn_mfma_f32_16x16x32_bf16(af[m], bfv[n], acc[m][n], 0, 0, 0);
  }

#pragma unroll
  for (int m = 0; m < 4; ++m) {
#pragma unroll
    for (int n = 0; n < 4; ++n) {
      const int r0 = tm * BM + wrow + m * 16 + fq * 4;
      const int c  = tn * BN + wcol + n * 16 + fr;
#pragma unroll
      for (int r = 0; r < 4; ++r) {
        float v = acc[m][n][r];
        long idx = (long)(r0 + r) * N + c;
        if constexpr (sizeof(OutT) == 2) C[idx] = f2bf(v);
        else                             C[idx] = v;
      }
    }
  }
}

// ---------------- gate finalize: sigmoid(raw + bias) ----------------
__global__ __launch_bounds__(256) void k_gates_fin(const float* __restrict__ raw,
                                                   const float* __restrict__ bg,
                                                   const float* __restrict__ bb,
                                                   float* __restrict__ alpha,
                                                   float* __restrict__ beta) {
  int i = blockIdx.x * 256 + threadIdx.x;
  if (i >= BT * NH) return;
  int bt = i >> 4, h = i & 15;
  float ga = raw[(long)bt * 128 + h] + bg[h];
  float gb = raw[(long)bt * 128 + 16 + h] + bb[h];
  alpha[i] = 1.f / (1.f + __expf(-ga));
  beta[i]  = 1.f / (1.f + __expf(-gb));
}

// ================= chunked WY scan (v2: MFMA block-solve, fused l2norm) =======
// Per chunk (t local 0..63, A_t = prod a = 2^{c_t}, k̂/q̂ = l2-normalized):
//   (I+L)[Wv|Tw] = [diag(b)V | diag(bA)K̂],  L[t,s]=b_t 2^{c_t-c_s}(k̂_s·k̂_t), s<t
//   Mq[t,s]=2^{c_t-c_s}(k̂_s·q̂_t) (s<=t);  Kd[t,:]=2^{c_63-c_t} k̂_t
//   O = Mq Wv + (diag(A)Q̂ - Mq Tw) S0^T = O_intra + Qeff S0^T
//   S_end = A63 S0 + S0 G + U,   G = -(Kd^T Tw),  U = Wv^T Kd
// Solve = blocked: Dinv_i = (I+L_ii)^{-1} (16x16, scalar), L~ = Dinv L (scalar),
// then W^T rows (wave-exclusive) via MFMA: R~T = RT·DinvT, W^T_i = R~T_i - W^T_j L~_ij^T.
// Outputs Qeff/G/U written PRE-SWIZZLED into own chunk's q/k/v slots (dead after read).
__global__ __launch_bounds__(256, 3) void k_prep(u16* __restrict__ qkv,
                                                 const float* __restrict__ alpha,
                                                 const float* __restrict__ beta,
                                                 float* __restrict__ A63G,
                                                 u16* __restrict__ ob) {
  __shared__ __align__(16) u16 Ks[64 * 64];
  __shared__ __align__(16) u16 WTs[128 * 64];   // rows 0-63: VbT->WvT; 64-127: KbT->TwT
  __shared__ __align__(16) u16 Lb[64 * 64];     // L (b-scaled), later -L~ in 6 sub-blocks
  __shared__ __align__(16) u16 MqS[64 * 64];
  __shared__ __align__(16) u16 KdT[64 * 64];
  __shared__ __align__(16) u16 Db[4 * 16 * DBS];
  __shared__ float cvec[64], Avec[64], bvec[64], nkinv[64], nqinv[64];

  const int unit = blockIdx.x;
  const int pair = unit >> 6, ch = unit & 63;
  const int b = pair >> 4, h = pair & 15;
  const int tid = threadIdx.x, l = tid & 63, w = tid >> 6;
  const int fr = l & 15, fq = l >> 4;
  const long t0 = (long)b * NT + (long)ch * CC;

  // ---- P0: issue global loads into regs; wave0 cumsum; init norm accums ----
  u16x8 kreg[2], vreg[2], qreg[2];
  int srow_[2], sseg_[2];
#pragma unroll
  for (int p = 0; p < 2; ++p) {
    int idx = p * 256 + tid;
    srow_[p] = idx >> 3; sseg_[p] = (idx & 7) * 8;
    long g = (t0 + srow_[p]) * 3072 + h * 64 + sseg_[p];
    qreg[p] = *(const u16x8*)&qkv[g];
    kreg[p] = *(const u16x8*)&qkv[g + 1024];
    vreg[p] = *(const u16x8*)&qkv[g + 2048];
  }
  const int ar = w * 16 + fr;
  u16x8 qa[2];
#pragma unroll
  for (int kk = 0; kk < 2; ++kk)
    qa[kk] = *(const u16x8*)&qkv[(t0 + ar) * 3072 + h * 64 + kk * 32 + fq * 8];

  if (tid < 64) { nkinv[tid] = 0.f; nqinv[tid] = 0.f; }
  if (w == 0) {
    float av = alpha[(t0 + l) * 16 + h];
    float bv = beta[(t0 + l) * 16 + h];
    float cl = __log2f(av);
#pragma unroll
    for (int d = 1; d < 64; d <<= 1) {
      float up = __shfl_up(cl, d);
      if (l >= d) cl += up;
    }
    float A = exp2f(cl);
    cvec[l] = cl; Avec[l] = A; bvec[l] = bv;
    if (l == 63) A63G[unit] = A;
  }
  __syncthreads();

  // ---- P1: stage Ks rows + VbT (b-scaled, transposed); norm partials ----
#pragma unroll
  for (int p = 0; p < 2; ++p) {
    int row = srow_[p], seg = sseg_[p];
    *(u16x8*)&Ks[row * 64 + swz(row, seg)] = kreg[p];
    float kss = 0.f, qss = 0.f;
    const float bs = bvec[row];
#pragma unroll
    for (int e = 0; e < 8; ++e) {
      float kf = bf2f(kreg[p][e]), qf = bf2f(qreg[p][e]);
      kss += kf * kf; qss += qf * qf;
      int c = seg + e;
      WTs[c * 64 + swz(c, row)] = f2bf(bs * bf2f(vreg[p][e]));
    }
    atomicAdd(&nkinv[row], kss);
    atomicAdd(&nqinv[row], qss);
  }
  __syncthreads();

  // ---- P2: inverse norms (1/max(||.||,1e-12) == rsqrt(max(ss,1e-24))) ----
  if (tid < 64)       nkinv[tid] = rsqrtf(fmaxf(nkinv[tid], 1e-24f));
  else if (tid < 128) nqinv[tid - 64] = rsqrtf(fmaxf(nqinv[tid - 64], 1e-24f));
  __syncthreads();

  // ---- P3: KK^T + QK^T MFMA; build KbT & KdT; L/Mq epilogue ----
  f32x4 akk[4], aqk[4];
#pragma unroll
  for (int n = 0; n < 4; ++n) { akk[n] = f32x4{0, 0, 0, 0}; aqk[n] = f32x4{0, 0, 0, 0}; }
  {
    bf16x8 afK[2], afQ[2];
#pragma unroll
    for (int kk = 0; kk < 2; ++kk) {
      afK[kk] = __builtin_bit_cast(bf16x8, *(const u16x8*)&Ks[ar * 64 + swz(ar, kk * 32 + fq * 8)]);
      afQ[kk] = __builtin_bit_cast(bf16x8, qa[kk]);
    }
#pragma unroll
    for (int n = 0; n < 4; ++n) {
      const int br = n * 16 + fr;
#pragma unroll
      for (int kk = 0; kk < 2; ++kk) {
        bf16x8 bk = __builtin_bit_cast(bf16x8, *(const u16x8*)&Ks[br * 64 + swz(br, kk * 32 + fq * 8)]);
        akk[n] = __builtin_amdgcn_mfma_f32_16x16x32_bf16(afK[kk], bk, akk[n], 0, 0, 0);
        aqk[n] = __builtin_amdgcn_mfma_f32_16x16x32_bf16(afQ[kk], bk, aqk[n], 0, 0, 0);
      }
    }
  }
  // KbT[64+j][t] = bA_t k̂[t][j];  KdT[j][t] = 2^(c63-c_t) k̂[t][j]
  {
    const int j = tid & 63, tg4 = tid >> 6;
    const float c63 = cvec[63];
    u16 kb[16], kd[16];
#pragma unroll
    for (int tt = 0; tt < 16; ++tt) {
      int t = tg4 * 16 + tt;
      float kv = bf2f(Ks[t * 64 + swz(t, j)]) * nkinv[t];
      kb[tt] = f2bf(bvec[t] * Avec[t] * kv);
      kd[tt] = f2bf(exp2f(c63 - cvec[t]) * kv);
    }
#pragma unroll
    for (int g8 = 0; g8 < 2; ++g8) {
      u16x8 o1, o2;
#pragma unroll
      for (int e = 0; e < 8; ++e) { o1[e] = kb[g8 * 8 + e]; o2[e] = kd[g8 * 8 + e]; }
      int colg = tg4 * 16 + g8 * 8;
      *(u16x8*)&WTs[(64 + j) * 64 + swz(64 + j, colg)] = o1;
      *(u16x8*)&KdT[j * 64 + swz(j, colg)] = o2;
    }
  }
#pragma unroll
  for (int n = 0; n < 4; ++n)
#pragma unroll
    for (int r = 0; r < 4; ++r) {
      const int t = w * 16 + fq * 4 + r;
      const int s = n * 16 + fr;
      const float e = exp2f(cvec[t] - cvec[s]);
      Lb[t * 64 + swz(t, s)] = (s < t) ? f2bf(bvec[t] * e * nkinv[t] * nkinv[s] * akk[n][r]) : (u16)0;
      MqS[t * 64 + swz(t, s)] = (s <= t) ? f2bf(e * nqinv[t] * nkinv[s] * aqk[n][r]) : (u16)0;
    }
  __syncthreads();

  // ---- P4: Dinv of 4 diagonal 16x16 blocks (wave0, 64 parallel columns) ----
  if (w == 0) {
    const int bi = l >> 4, c = l & 15;
    const int rb = bi * 16;
    float x[16];
#pragma unroll
    for (int u = 0; u < 16; ++u) {
      float a2 = (u == c) ? 1.f : 0.f;
#pragma unroll
      for (int s = 0; s < u; ++s)
        a2 -= bf2f(Lb[(rb + u) * 64 + swz(rb + u, rb + s)]) * x[s];
      x[u] = a2;
    }
#pragma unroll
    for (int u = 0; u < 16; ++u)
      Db[bi * 16 * DBS + u * DBS + c] = f2bf(x[u]);
  }
  __syncthreads();

  // ---- P5: L~ = Dinv.L (scalar, store NEGATED); R~T = RT.DinvT (MFMA) ----
  float ltil[6];
  {
    const int pbi[6] = {1, 2, 2, 3, 3, 3}, pbj[6] = {0, 0, 1, 0, 1, 2};
    const int tt = tid >> 4, s = tid & 15;
#pragma unroll
    for (int e = 0; e < 6; ++e) {
      int bi = pbi[e], bj = pbj[e];
      float a2 = 0.f;
#pragma unroll
      for (int u = 0; u < 16; ++u)
        a2 += bf2f(Db[bi * 16 * DBS + tt * DBS + u]) *
              bf2f(Lb[(bi * 16 + u) * 64 + swz(bi * 16 + u, bj * 16 + s)]);
      ltil[e] = a2;
    }
  }
  f32x4 rtacc[2][4];
#pragma unroll
  for (int rt2 = 0; rt2 < 2; ++rt2) {
    const int rrow = (w * 2 + rt2) * 16 + fr;
#pragma unroll
    for (int bi = 0; bi < 4; ++bi) {
      bf16x8 a2 = (fq < 2)
        ? __builtin_bit_cast(bf16x8, *(const u16x8*)&WTs[rrow * 64 + swz(rrow, bi * 16 + fq * 8)])
        : zfrag();
      bf16x8 b2 = (fq < 2)
        ? __builtin_bit_cast(bf16x8, *(const u16x8*)&Db[bi * 16 * DBS + fr * DBS + fq * 8])
        : zfrag();
      rtacc[rt2][bi] = __builtin_amdgcn_mfma_f32_16x16x32_bf16(a2, b2, f32x4{0, 0, 0, 0}, 0, 0, 0);
    }
  }
  __syncthreads();   // all L~/R~ reads done before overwrites
  {
    const int pbi[6] = {1, 2, 2, 3, 3, 3}, pbj[6] = {0, 0, 1, 0, 1, 2};
    const int tt = tid >> 4, s = tid & 15;
#pragma unroll
    for (int e = 0; e < 6; ++e)
      Lb[(pbi[e] * 16 + tt) * 64 + swz(pbi[e] * 16 + tt, pbj[e] * 16 + s)] = f2bf(-ltil[e]);
  }
#pragma unroll
  for (int rt2 = 0; rt2 < 2; ++rt2)
#pragma unroll
    for (int bi = 0; bi < 4; ++bi)
#pragma unroll
      for (int r = 0; r < 4; ++r) {
        int rr = (w * 2 + rt2) * 16 + fq * 4 + r;
        WTs[rr * 64 + swz(rr, bi * 16 + fr)] = f2bf(rtacc[rt2][bi][r]);
      }
  __syncthreads();

  // ---- P6: 3-step MFMA substitution (row-tiles wave-exclusive, no barriers) ----
#pragma unroll
  for (int rt2 = 0; rt2 < 2; ++rt2) {
    const int rrow = (w * 2 + rt2) * 16 + fr;
    const int wr0 = (w * 2 + rt2) * 16 + fq * 4;
#pragma unroll
    for (int i = 1; i < 4; ++i) {
      f32x4 a2;
#pragma unroll
      for (int r = 0; r < 4; ++r)
        a2[r] = bf2f(WTs[(wr0 + r) * 64 + swz(wr0 + r, i * 16 + fr)]);
      {
        bf16x8 af = __builtin_bit_cast(bf16x8, *(const u16x8*)&WTs[rrow * 64 + swz(rrow, fq * 8)]);
        bf16x8 bf_;
        if (i == 1) bf_ = (fq < 2)
          ? __builtin_bit_cast(bf16x8, *(const u16x8*)&Lb[(16 + fr) * 64 + swz(16 + fr, fq * 8)])
          : zfrag();
        else bf_ = __builtin_bit_cast(bf16x8, *(const u16x8*)&Lb[(i * 16 + fr) * 64 + swz(i * 16 + fr, fq * 8)]);
        a2 = __builtin_amdgcn_mfma_f32_16x16x32_bf16(af, bf_, a2, 0, 0, 0);
      }
      if (i == 3) {
        bf16x8 af = __builtin_bit_cast(bf16x8, *(const u16x8*)&WTs[rrow * 64 + swz(rrow, 32 + fq * 8)]);
        bf16x8 bf_ = (fq < 2)
          ? __builtin_bit_cast(bf16x8, *(const u16x8*)&Lb[(48 + fr) * 64 + swz(48 + fr, 32 + fq * 8)])
          : zfrag();
        a2 = __builtin_amdgcn_mfma_f32_16x16x32_bf16(af, bf_, a2, 0, 0, 0);
      }
#pragma unroll
      for (int r = 0; r < 4; ++r)
        WTs[(wr0 + r) * 64 + swz(wr0 + r, i * 16 + fr)] = f2bf(a2[r]);
    }
  }
  __syncthreads();

  // ---- P7: final 4 GEMMs + in-place swizzled epilogue ----
  u16 qpre[4][4];
#pragma unroll
  for (int n = 0; n < 4; ++n)
#pragma unroll
    for (int r = 0; r < 4; ++r)
      qpre[n][r] = qkv[(t0 + w * 16 + fq * 4 + r) * 3072 + h * 64 + n * 16 + fr];

  f32x4 aG[4], aU[4], aQe[4], aOi[4];
#pragma unroll
  for (int n = 0; n < 4; ++n) {
    aG[n] = f32x4{0, 0, 0, 0}; aU[n] = f32x4{0, 0, 0, 0};
    aQe[n] = f32x4{0, 0, 0, 0}; aOi[n] = f32x4{0, 0, 0, 0};
  }
  {
    bf16x8 aKd[2], aWv[2], aMq[2];
#pragma unroll
    for (int kk = 0; kk < 2; ++kk) {
      aKd[kk] = __builtin_bit_cast(bf16x8, *(const u16x8*)&KdT[ar * 64 + swz(ar, kk * 32 + fq * 8)]);
      aWv[kk] = __builtin_bit_cast(bf16x8, *(const u16x8*)&WTs[ar * 64 + swz(ar, kk * 32 + fq * 8)]);
      aMq[kk] = __builtin_bit_cast(bf16x8, *(const u16x8*)&MqS[ar * 64 + swz(ar, kk * 32 + fq * 8)]);
    }
#pragma unroll
    for (int n = 0; n < 4; ++n) {
      const int br = n * 16 + fr;
#pragma unroll
      for (int kk = 0; kk < 2; ++kk) {
        bf16x8 bTw = __builtin_bit_cast(bf16x8, *(const u16x8*)&WTs[(64 + br) * 64 + swz(64 + br, kk * 32 + fq * 8)]);
        bf16x8 bKd = __builtin_bit_cast(bf16x8, *(const u16x8*)&KdT[br * 64 + swz(br, kk * 32 + fq * 8)]);
        bf16x8 bWv = __builtin_bit_cast(bf16x8, *(const u16x8*)&WTs[br * 64 + swz(br, kk * 32 + fq * 8)]);
        aG[n]  = __builtin_amdgcn_mfma_f32_16x16x32_bf16(aKd[kk], bTw, aG[n], 0, 0, 0);
        aU[n]  = __builtin_amdgcn_mfma_f32_16x16x32_bf16(aWv[kk], bKd, aU[n], 0, 0, 0);
        aQe[n] = __builtin_amdgcn_mfma_f32_16x16x32_bf16(aMq[kk], bTw, aQe[n], 0, 0, 0);
        aOi[n] = __builtin_amdgcn_mfma_f32_16x16x32_bf16(aMq[kk], bWv, aOi[n], 0, 0, 0);
      }
    }
  }
  asm volatile("s_waitcnt vmcnt(0)" ::: "memory");   // qpre loaded before slot overwrite
  __builtin_amdgcn_sched_barrier(0);
#pragma unroll
  for (int n = 0; n < 4; ++n)
#pragma unroll
    for (int r = 0; r < 4; ++r) {
      const int i = w * 16 + fq * 4 + r;
      const int cn = n * 16 + fr;
      const long grow = (t0 + i) * 3072 + h * 64 + swz(i, cn);   // PRE-SWIZZLED
      qkv[grow]        = f2bf(Avec[i] * nqinv[i] * bf2f(qpre[n][r]) - aQe[n][r]);  // Qeff
      qkv[grow + 1024] = f2bf(-aG[n][r]);                                          // G
      qkv[grow + 2048] = f2bf(aU[n][r]);                                           // U
      ob[(t0 + i) * 1024 + h * 64 + cn] = f2bf(aOi[n][r]);                         // O_intra (linear)
    }
}

// ---------------- sequential chunk recurrence (double-buffered async staging) --
// 64 blocks (one per pair) x 256 threads; 64 sequential chunk steps.
// Qeff/G/U (pre-swizzled in qkv slots) + O_intra staged via global_load_lds,
// double-buffered, counted vmcnt(8) (never drained mid-loop).
__global__ __launch_bounds__(256) void k_seq(const u16* __restrict__ qkv,
                                             const float* __restrict__ A63G,
                                             u16* __restrict__ ob) {
  __shared__ __align__(16) u16 Sb[64 * 64];
  __shared__ __align__(16) u16 stg[2][4][64 * 64];   // [buf][Qe,G,U,Ob][..]
  __shared__ float a63s[64];
  const int pair = blockIdx.x;
  const int b = pair >> 4, h = pair & 15;
  const int tid = threadIdx.x, l = tid & 63, w = tid >> 6;
  const int fr = l & 15, fq = l >> 4;
  const int ar = w * 16 + fr;

  auto stage = [&](int c, int bi) {
    const long tg = (long)b * NT + (long)c * CC;
#pragma unroll
    for (int m = 0; m < 4; ++m)
#pragma unroll
      for (int p = 0; p < 2; ++p) {
        int idx = p * 256 + tid;
        int row = idx >> 3, seg = (idx & 7) * 8;
        const u16* src = (m < 3)
          ? &qkv[(tg + row) * 3072 + m * 1024 + h * 64 + seg]
          : &ob[(tg + row) * 1024 + h * 64 + seg];
        gload_lds16(src, &stg[bi][m][p * 2048 + w * 512]);
      }
  };

  if (tid < 64) a63s[tid] = A63G[pair * 64 + tid];
  for (int i = tid; i < 4096; i += 256) Sb[i] = 0;
  stage(0, 0);
  f32x4 sacc[4];
#pragma unroll
  for (int n = 0; n < 4; ++n) sacc[n] = f32x4{0, 0, 0, 0};
  asm volatile("s_waitcnt lgkmcnt(0)" ::: "memory");
  __builtin_amdgcn_sched_barrier(0);

  for (int c = 0; c < NCH; ++c) {
    const int bi = c & 1;
    const long tg = (long)b * NT + (long)c * CC;
    if (c + 1 < NCH) {
      stage(c + 1, bi ^ 1);
      asm volatile("s_waitcnt vmcnt(8)" ::: "memory");
    } else {
      asm volatile("s_waitcnt vmcnt(0)" ::: "memory");
    }
    __builtin_amdgcn_sched_barrier(0);
    __builtin_amdgcn_s_barrier();
    __builtin_amdgcn_sched_barrier(0);

    const u16* Qe = stg[bi][0];
    const u16* Gm = stg[bi][1];
    const u16* Um = stg[bi][2];
    const u16* Obl = stg[bi][3];

    // O_cross[t][d] = sum_j Qeff[t][j] S[d][j]
    bf16x8 aq[2];
#pragma unroll
    for (int kk = 0; kk < 2; ++kk)
      aq[kk] = __builtin_bit_cast(bf16x8, *(const u16x8*)&Qe[ar * 64 + swz(ar, kk * 32 + fq * 8)]);
    f32x4 ao[4];
#pragma unroll
    for (int n = 0; n < 4; ++n) ao[n] = f32x4{0, 0, 0, 0};
#pragma unroll
    for (int n = 0; n < 4; ++n) {
      const int br = n * 16 + fr;
#pragma unroll
      for (int kk = 0; kk < 2; ++kk) {
        bf16x8 sb = __builtin_bit_cast(bf16x8, *(const u16x8*)&Sb[br * 64 + swz(br, kk * 32 + fq * 8)]);
        ao[n] = __builtin_amdgcn_mfma_f32_16x16x32_bf16(aq[kk], sb, ao[n], 0, 0, 0);
      }
    }
    // S update: sacc = A63*sacc + S.G (+U below)
    bf16x8 as_[2];
#pragma unroll
    for (int kk = 0; kk < 2; ++kk)
      as_[kk] = __builtin_bit_cast(bf16x8, *(const u16x8*)&Sb[ar * 64 + swz(ar, kk * 32 + fq * 8)]);
    const float A63 = a63s[c];
#pragma unroll
    for (int n = 0; n < 4; ++n) {
#pragma unroll
      for (int r = 0; r < 4; ++r) sacc[n][r] *= A63;
      const int br = n * 16 + fr;
#pragma unroll
      for (int kk = 0; kk < 2; ++kk) {
        bf16x8 g = __builtin_bit_cast(bf16x8, *(const u16x8*)&Gm[br * 64 + swz(br, kk * 32 + fq * 8)]);
        sacc[n] = __builtin_amdgcn_mfma_f32_16x16x32_bf16(as_[kk], g, sacc[n], 0, 0, 0);
      }
    }
    // +U, O writeout
#pragma unroll
    for (int n = 0; n < 4; ++n)
#pragma unroll
      for (int r = 0; r < 4; ++r) {
        const int i = w * 16 + fq * 4 + r;
        const int cn = n * 16 + fr;
        sacc[n][r] += bf2f(Um[i * 64 + swz(i, cn)]);
        float o = bf2f(Obl[i * 64 + cn]) + ao[n][r];
        ob[(tg + i) * 1024 + h * 64 + cn] = f2bf(o);
      }
    __builtin_amdgcn_s_barrier();   // all waves done reading Sb
#pragma unroll
    for (int n = 0; n < 4; ++n)
#pragma unroll
      for (int r = 0; r < 4; ++r) {
        const int d = w * 16 + fq * 4 + r, j = n * 16 + fr;
        Sb[d * 64 + swz(d, j)] = f2bf(sacc[n][r]);
      }
    asm volatile("s_waitcnt lgkmcnt(0)" ::: "memory");
    __builtin_amdgcn_sched_barrier(0);
  }
}

extern "C" void kernel_launch(void* const* d_in, const int* in_sizes, int n_in,
                              void* d_out, int out_size, void* d_ws, size_t ws_size,
                              hipStream_t stream) {
  const float* x    = (const float*)d_in[0];
  const float* Wqkv = (const float*)d_in[1];
  const float* Wg   = (const float*)d_in[2];
  const float* bg   = (const float*)d_in[3];
  const float* Wb   = (const float*)d_in[4];
  const float* bb   = (const float*)d_in[5];
  const float* Wout = (const float*)d_in[6];
  float* out = (float*)d_out;

  char* ws = (char*)d_ws;
  u16* xb    = (u16*)ws;                               // 16384*1024   (32MB)
  u16* wqkvb = xb    + (long)BT * NDIM;                // 3072*1024    (6MB)
  u16* woutb = wqkvb + (long)3072 * 1024;              // 1024*1024    (2MB)
  u16* wgbb  = woutb + (long)1024 * 1024;              // 128*1024
  u16* qkvb  = wgbb  + (long)128 * 1024;               // 16384*3072   (96MB)
  u16* ob    = qkvb  + (long)BT * 3072;                // 16384*1024   (32MB)
  float* graw  = (float*)(ob + (long)BT * NDIM);       // 16384*128    (8MB)
  float* alpha = graw + (long)BT * 128;                // 16384*16     (1MB)
  float* beta  = alpha + (long)BT * NH;                // 16384*16     (1MB)
  float* A63G  = graw;   // reuse: graw dead after k_gates_fin (needs 16KB)

  // 1. converts
  k_f32_to_bf16<<<(BT * (long)NDIM / 4 + 255) / 256, 256, 0, stream>>>(x, xb, BT * (long)NDIM / 4);
  k_f32_to_bf16<<<(3072L * 1024 / 4 + 255) / 256, 256, 0, stream>>>(Wqkv, wqkvb, 3072L * 1024 / 4);
  k_f32_to_bf16<<<(1024L * 1024 / 4 + 255) / 256, 256, 0, stream>>>(Wout, woutb, 1024L * 1024 / 4);
  k_build_wgb<<<(128 * 1024) / 256, 256, 0, stream>>>(Wg, Wb, wgbb);

  // 2. qkv GEMM
  k_gemm_bt<u16><<<dim3(3072 / 128, BT / 128), 256, 0, stream>>>(xb, wqkvb, qkvb, BT, 3072, NDIM);

  // 3. gates GEMM + finalize
  k_gemm_bt<float><<<dim3(1, BT / 128), 256, 0, stream>>>(xb, wgbb, graw, BT, 128, NDIM);
  k_gates_fin<<<(BT * NH + 255) / 256, 256, 0, stream>>>(graw, bg, bb, alpha, beta);

  // 4. chunked WY: parallel precompute (fused l2norm, MFMA solve) + sequential GEMMs
  k_prep<<<NU, 256, 0, stream>>>(qkvb, alpha, beta, A63G, ob);
  k_seq<<<NPAIR, 256, 0, stream>>>(qkvb, A63G, ob);

  // 5. out GEMM
  k_gemm_bt<float><<<dim3(NDIM / 128, BT / 128), 256, 0, stream>>>(ob, woutb, out, BT, NDIM, NDIM);
}

// Round 6
// 443.796 us; speedup vs baseline: 6.1640x; 1.0962x over previous
//
#include <hip/hip_runtime.h>
#include <hip/hip_bf16.h>

// Problem constants
#define NB   4
#define NT   4096
#define BT   16384   // NB*NT
#define NDIM 1024
#define NH   16
#define NDH  64
#define CC   64              // chunk size (time steps)
#define NCH  (NT / CC)       // 64 chunks per pair
#define NPAIR 64             // B*H
#define NU   (NPAIR * NCH)   // 4096 units
#define DBS  24              // Db row stride (u16 elems), padded for banks

using u16 = unsigned short;
typedef __bf16 bf16x8 __attribute__((ext_vector_type(8)));
typedef float f32x4 __attribute__((ext_vector_type(4)));
typedef unsigned short u16x8 __attribute__((ext_vector_type(8)));
typedef unsigned short u16x4 __attribute__((ext_vector_type(4)));

__device__ __forceinline__ float bf2f(u16 b) { return __uint_as_float(((unsigned)b) << 16); }
__device__ __forceinline__ u16 f2bf(float f) {
  return __builtin_bit_cast(u16, __float2bfloat16(f));
}
// LDS row swizzle (u16-element index, 8-elem granular): breaks stride-128B bank conflicts
__device__ __forceinline__ int swz(int row, int e) { return e ^ ((row & 7) << 3); }
__device__ __forceinline__ bf16x8 zfrag() {
  u16x8 z = {0, 0, 0, 0, 0, 0, 0, 0};
  return __builtin_bit_cast(bf16x8, z);
}

// ---------------- convert fp32 -> bf16 (vectorized) ----------------
__global__ __launch_bounds__(256) void k_f32_to_bf16(const float* __restrict__ in,
                                                     u16* __restrict__ out, long n4) {
  long i = (long)blockIdx.x * blockDim.x + threadIdx.x;
  if (i >= n4) return;
  float4 f = reinterpret_cast<const float4*>(in)[i];
  u16x4 o;
  o.x = f2bf(f.x); o.y = f2bf(f.y); o.z = f2bf(f.z); o.w = f2bf(f.w);
  reinterpret_cast<u16x4*>(out)[i] = o;
}

// ---------------- build padded gate weight matrix (128 x 1024 bf16) ----------------
__global__ __launch_bounds__(256) void k_build_wgb(const float* __restrict__ Wg,
                                                   const float* __restrict__ Wb,
                                                   u16* __restrict__ out) {
  int i = blockIdx.x * 256 + threadIdx.x;
  int row = i >> 10, col = i & 1023;
  float f = 0.f;
  if (row < 16)       f = Wg[row * 1024 + col];
  else if (row < 32)  f = Wb[(row - 16) * 1024 + col];
  out[i] = f2bf(f);
}

// ---------------- global_load_lds helper ----------------
typedef unsigned int u32_as1 __attribute__((address_space(1)));
typedef unsigned int u32_as3 __attribute__((address_space(3)));
__device__ __forceinline__ void gload_lds16(const void* g, void* l) {
  __builtin_amdgcn_global_load_lds((const u32_as1*)g, (u32_as3*)l, 16, 0, 0);
}

// ---------------- bf16 GEMM (small-N path): C(MxN) = A(MxK) @ B(NxK)^T -------
template <typename OutT>
__global__ __launch_bounds__(256) void k_gemm_bt(const u16* __restrict__ A,
                                                 const u16* __restrict__ B,
                                                 OutT* __restrict__ C,
                                                 int M, int N, int K) {
  constexpr int BM = 128, BN = 128, BK = 32;
  __shared__ __align__(16) u16 As[BM * BK];
  __shared__ __align__(16) u16 Bs[BN * BK];
  const int tid = threadIdx.x;
  const int l = tid & 63, w = tid >> 6;
  const int tn = blockIdx.x, tm = blockIdx.y;
  const long a0 = (long)tm * BM * K;
  const long b0 = (long)tn * BN * K;
  const int srow = tid >> 2;
  const int scol = (tid & 3) << 3;
  const int wrow = (w >> 1) << 6;
  const int wcol = (w & 1) << 6;
  const int fr = l & 15, fq = l >> 4;

  f32x4 acc[4][4];
#pragma unroll
  for (int m = 0; m < 4; ++m)
#pragma unroll
    for (int n = 0; n < 4; ++n) acc[m][n] = f32x4{0.f, 0.f, 0.f, 0.f};

  for (int kk = 0; kk < K; kk += BK) {
    __syncthreads();
    const u16* gA = A + a0 + (long)srow * K + kk + scol;
    const u16* gB = B + b0 + (long)srow * K + kk + scol;
    gload_lds16(gA,                &As[(w * 16) * BK]);
    gload_lds16(gA + 64 * (long)K, &As[(64 + w * 16) * BK]);
    gload_lds16(gB,                &Bs[(w * 16) * BK]);
    gload_lds16(gB + 64 * (long)K, &Bs[(64 + w * 16) * BK]);
    __syncthreads();

    bf16x8 af[4], bfv[4];
#pragma unroll
    for (int m = 0; m < 4; ++m)
      af[m] = *(const bf16x8*)&As[(wrow + m * 16 + fr) * BK + (fq << 3)];
#pragma unroll
    for (int n = 0; n < 4; ++n)
      bfv[n] = *(const bf16x8*)&Bs[(wcol + n * 16 + fr) * BK + (fq << 3)];
#pragma unroll
    for (int m = 0; m < 4; ++m)
#pragma unroll
      for (int n = 0; n < 4; ++n)
        acc[m][n] = __builtin_amdgcn_mfma_f32_16x16x32_bf16(af[m], bfv[n], acc[m][n], 0, 0, 0);
  }

#pragma unroll
  for (int m = 0; m < 4; ++m) {
#pragma unroll
    for (int n = 0; n < 4; ++n) {
      const int r0 = tm * BM + wrow + m * 16 + fq * 4;
      const int c  = tn * BN + wcol + n * 16 + fr;
#pragma unroll
      for (int r = 0; r < 4; ++r) {
        float v = acc[m][n][r];
        long idx = (long)(r0 + r) * N + c;
        if constexpr (sizeof(OutT) == 2) C[idx] = f2bf(v);
        else                             C[idx] = v;
      }
    }
  }
}

// ============ 256x256-tile 8-phase bf16 GEMM: C = A(MxK) @ B(NxK)^T ==========
// 512 threads = 8 waves (2M x 4N); per-wave 128x64 output; BK=64 split into two
// 32-wide K-slices (ks). LDS [2 dbuf][2 ks][256x32] per operand, XOR-swizzled
// (c16 ^= (row>>2)&3 -> 2-way bank access, free). Staging via linear-dest
// global_load_lds with pre-swizzled global source. Counted vmcnt(4) twice per
// K-tile (never 0 until final drain); raw s_barrier; setprio around MFMA.
template <typename OutT>
__global__ __launch_bounds__(512, 2) void k_gemm256(const u16* __restrict__ A,
                                                    const u16* __restrict__ B,
                                                    OutT* __restrict__ C,
                                                    int M, int N, int K) {
  __shared__ __align__(16) u16 As[2][2][256 * 32];
  __shared__ __align__(16) u16 Bs[2][2][256 * 32];
  const int tid = threadIdx.x;
  const int l = tid & 63, w = tid >> 6;
  const int wm = w >> 2, wn = w & 3;          // 2 x 4 wave grid
  const int fr = l & 15, fq = l >> 4;
  // bijective XCD swizzle (gridDim.x % 8 == 0 guaranteed by launch)
  const int nwg = gridDim.x;
  const int cpx = nwg >> 3;
  const int bid = blockIdx.x;
  const int sbid = (bid & 7) * cpx + (bid >> 3);
  const int ntn = N >> 8;
  const int tm = sbid / ntn, tn = sbid - tm * ntn;
  const long a0 = (long)tm * 256 * K;
  const long b0 = (long)tn * 256 * K;
  // staging: thread t covers rows r*128 + (t>>2), 16B chunk (t&3); source col
  // pre-swizzled so linear LDS dest yields swizzled layout.
  const int srow0 = tid >> 2;
  const int scol8 = (((tid & 3) ^ ((tid >> 4) & 3)) << 3);
  // fragment read column swizzle (u16 units); (row>>2)&3 == (fr>>2)&3 for all
  // fragment rows (wm*128, wn*64, m*16, n*16 all ≡ 0 mod 4).
  const int cswz = ((fq ^ ((fr >> 2) & 3)) << 3);
  const int NKT = K >> 6;

  auto stage_half = [&](int kt, int buf, int hf) {
    // hf: 0 = A ks0, 1 = B ks0, 2 = A ks1, 3 = B ks1
    const int ks = hf >> 1;
    const u16* Gp = (hf & 1) ? B : A;
    const long g0 = ((hf & 1) ? b0 : a0) + (long)kt * 64 + ks * 32 + scol8;
    u16* lb = (hf & 1) ? &Bs[buf][ks][w * 512] : &As[buf][ks][w * 512];
#pragma unroll
    for (int r = 0; r < 2; ++r)
      gload_lds16(Gp + g0 + (long)(r * 128 + srow0) * K, lb + r * 4096);
  };

  f32x4 acc[8][4];
#pragma unroll
  for (int m = 0; m < 8; ++m)
#pragma unroll
    for (int n = 0; n < 4; ++n) acc[m][n] = f32x4{0.f, 0.f, 0.f, 0.f};

  stage_half(0, 0, 0); stage_half(0, 0, 1); stage_half(0, 0, 2); stage_half(0, 0, 3);

  for (int kt = 0; kt < NKT; ++kt) {
    const int bi = kt & 1;
    const bool pf = (kt + 1 < NKT);
    // ---- entry: A-ks0 + B-ks0 of kt ready (oldest 4 loads) ----
    asm volatile("s_waitcnt vmcnt(4)" ::: "memory");
    __builtin_amdgcn_sched_barrier(0);
    __builtin_amdgcn_s_barrier();
    __builtin_amdgcn_sched_barrier(0);
    {
      const u16* ap = &As[bi][0][(wm * 128 + fr) * 32 + cswz];
      const u16* bp = &Bs[bi][0][(wn * 64 + fr) * 32 + cswz];
      bf16x8 bfr[4], afr[4];
#pragma unroll
      for (int n = 0; n < 4; ++n) bfr[n] = *(const bf16x8*)(bp + n * 512);
#pragma unroll
      for (int m = 0; m < 4; ++m) afr[m] = *(const bf16x8*)(ap + m * 512);
      if (pf) stage_half(kt + 1, bi ^ 1, 0);
      __builtin_amdgcn_s_setprio(1);
#pragma unroll
      for (int m = 0; m < 4; ++m)
#pragma unroll
        for (int n = 0; n < 4; ++n)
          acc[m][n] = __builtin_amdgcn_mfma_f32_16x16x32_bf16(afr[m], bfr[n], acc[m][n], 0, 0, 0);
      __builtin_amdgcn_s_setprio(0);
#pragma unroll
      for (int m = 0; m < 4; ++m) afr[m] = *(const bf16x8*)(ap + (4 + m) * 512);
      if (pf) stage_half(kt + 1, bi ^ 1, 1);
      __builtin_amdgcn_s_setprio(1);
#pragma unroll
      for (int m = 0; m < 4; ++m)
#pragma unroll
        for (int n = 0; n < 4; ++n)
          acc[4 + m][n] = __builtin_amdgcn_mfma_f32_16x16x32_bf16(afr[m], bfr[n], acc[4 + m][n], 0, 0, 0);
      __builtin_amdgcn_s_setprio(0);
    }
    // ---- mid: A-ks1 + B-ks1 of kt ready ----
    if (pf) { asm volatile("s_waitcnt vmcnt(4)" ::: "memory"); }
    else    { asm volatile("s_waitcnt vmcnt(0)" ::: "memory"); }
    __builtin_amdgcn_sched_barrier(0);
    __builtin_amdgcn_s_barrier();
    __builtin_amdgcn_sched_barrier(0);
    {
      const u16* ap = &As[bi][1][(wm * 128 + fr) * 32 + cswz];
      const u16* bp = &Bs[bi][1][(wn * 64 + fr) * 32 + cswz];
      bf16x8 bfr[4], afr[4];
#pragma unroll
      for (int n = 0; n < 4; ++n) bfr[n] = *(const bf16x8*)(bp + n * 512);
#pragma unroll
      for (int m = 0; m < 4; ++m) afr[m] = *(const bf16x8*)(ap + m * 512);
      if (pf) stage_half(kt + 1, bi ^ 1, 2);
      __builtin_amdgcn_s_setprio(1);
#pragma unroll
      for (int m = 0; m < 4; ++m)
#pragma unroll
        for (int n = 0; n < 4; ++n)
          acc[m][n] = __builtin_amdgcn_mfma_f32_16x16x32_bf16(afr[m], bfr[n], acc[m][n], 0, 0, 0);
      __builtin_amdgcn_s_setprio(0);
#pragma unroll
      for (int m = 0; m < 4; ++m) afr[m] = *(const bf16x8*)(ap + (4 + m) * 512);
      if (pf) stage_half(kt + 1, bi ^ 1, 3);
      __builtin_amdgcn_s_setprio(1);
#pragma unroll
      for (int m = 0; m < 4; ++m)
#pragma unroll
        for (int n = 0; n < 4; ++n)
          acc[4 + m][n] = __builtin_amdgcn_mfma_f32_16x16x32_bf16(afr[m], bfr[n], acc[4 + m][n], 0, 0, 0);
      __builtin_amdgcn_s_setprio(0);
    }
  }

#pragma unroll
  for (int m = 0; m < 8; ++m)
#pragma unroll
    for (int n = 0; n < 4; ++n) {
      const int row0 = tm * 256 + wm * 128 + m * 16 + fq * 4;
      const int col  = tn * 256 + wn * 64 + n * 16 + fr;
#pragma unroll
      for (int r = 0; r < 4; ++r) {
        long idx = (long)(row0 + r) * N + col;
        if constexpr (sizeof(OutT) == 2) C[idx] = f2bf(acc[m][n][r]);
        else                             C[idx] = acc[m][n][r];
      }
    }
}

// ---------------- gate finalize: sigmoid(raw + bias) ----------------
__global__ __launch_bounds__(256) void k_gates_fin(const float* __restrict__ raw,
                                                   const float* __restrict__ bg,
                                                   const float* __restrict__ bb,
                                                   float* __restrict__ alpha,
                                                   float* __restrict__ beta) {
  int i = blockIdx.x * 256 + threadIdx.x;
  if (i >= BT * NH) return;
  int bt = i >> 4, h = i & 15;
  float ga = raw[(long)bt * 128 + h] + bg[h];
  float gb = raw[(long)bt * 128 + 16 + h] + bb[h];
  alpha[i] = 1.f / (1.f + __expf(-ga));
  beta[i]  = 1.f / (1.f + __expf(-gb));
}

// ================= chunked WY scan (MFMA block-solve, fused l2norm) =======
// Per chunk (t local 0..63, A_t = prod a = 2^{c_t}, k̂/q̂ = l2-normalized):
//   (I+L)[Wv|Tw] = [diag(b)V | diag(bA)K̂],  L[t,s]=b_t 2^{c_t-c_s}(k̂_s·k̂_t), s<t
//   Mq[t,s]=2^{c_t-c_s}(k̂_s·q̂_t) (s<=t);  Kd[t,:]=2^{c_63-c_t} k̂_t
//   O = Mq Wv + (diag(A)Q̂ - Mq Tw) S0^T = O_intra + Qeff S0^T
//   S_end = A63 S0 + S0 G + U,   G = -(Kd^T Tw),  U = Wv^T Kd
__global__ __launch_bounds__(256, 3) void k_prep(u16* __restrict__ qkv,
                                                 const float* __restrict__ alpha,
                                                 const float* __restrict__ beta,
                                                 float* __restrict__ A63G,
                                                 u16* __restrict__ ob) {
  __shared__ __align__(16) u16 Ks[64 * 64];
  __shared__ __align__(16) u16 WTs[128 * 64];   // rows 0-63: VbT->WvT; 64-127: KbT->TwT
  __shared__ __align__(16) u16 Lb[64 * 64];     // L (b-scaled), later -L~ in 6 sub-blocks
  __shared__ __align__(16) u16 MqS[64 * 64];
  __shared__ __align__(16) u16 KdT[64 * 64];
  __shared__ __align__(16) u16 Db[4 * 16 * DBS];
  __shared__ float cvec[64], Avec[64], bvec[64], nkinv[64], nqinv[64];

  const int unit = blockIdx.x;
  const int pair = unit >> 6, ch = unit & 63;
  const int b = pair >> 4, h = pair & 15;
  const int tid = threadIdx.x, l = tid & 63, w = tid >> 6;
  const int fr = l & 15, fq = l >> 4;
  const long t0 = (long)b * NT + (long)ch * CC;

  // ---- P0: issue global loads into regs; wave0 cumsum; init norm accums ----
  u16x8 kreg[2], vreg[2], qreg[2];
  int srow_[2], sseg_[2];
#pragma unroll
  for (int p = 0; p < 2; ++p) {
    int idx = p * 256 + tid;
    srow_[p] = idx >> 3; sseg_[p] = (idx & 7) * 8;
    long g = (t0 + srow_[p]) * 3072 + h * 64 + sseg_[p];
    qreg[p] = *(const u16x8*)&qkv[g];
    kreg[p] = *(const u16x8*)&qkv[g + 1024];
    vreg[p] = *(const u16x8*)&qkv[g + 2048];
  }
  const int ar = w * 16 + fr;
  u16x8 qa[2];
#pragma unroll
  for (int kk = 0; kk < 2; ++kk)
    qa[kk] = *(const u16x8*)&qkv[(t0 + ar) * 3072 + h * 64 + kk * 32 + fq * 8];

  if (tid < 64) { nkinv[tid] = 0.f; nqinv[tid] = 0.f; }
  if (w == 0) {
    float av = alpha[(t0 + l) * 16 + h];
    float bv = beta[(t0 + l) * 16 + h];
    float cl = __log2f(av);
#pragma unroll
    for (int d = 1; d < 64; d <<= 1) {
      float up = __shfl_up(cl, d);
      if (l >= d) cl += up;
    }
    float A = exp2f(cl);
    cvec[l] = cl; Avec[l] = A; bvec[l] = bv;
    if (l == 63) A63G[unit] = A;
  }
  __syncthreads();

  // ---- P1: stage Ks rows + VbT (b-scaled, transposed); norm partials ----
#pragma unroll
  for (int p = 0; p < 2; ++p) {
    int row = srow_[p], seg = sseg_[p];
    *(u16x8*)&Ks[row * 64 + swz(row, seg)] = kreg[p];
    float kss = 0.f, qss = 0.f;
    const float bs = bvec[row];
#pragma unroll
    for (int e = 0; e < 8; ++e) {
      float kf = bf2f(kreg[p][e]), qf = bf2f(qreg[p][e]);
      kss += kf * kf; qss += qf * qf;
      int c = seg + e;
      WTs[c * 64 + swz(c, row)] = f2bf(bs * bf2f(vreg[p][e]));
    }
    atomicAdd(&nkinv[row], kss);
    atomicAdd(&nqinv[row], qss);
  }
  __syncthreads();

  // ---- P2: inverse norms ----
  if (tid < 64)       nkinv[tid] = rsqrtf(fmaxf(nkinv[tid], 1e-24f));
  else if (tid < 128) nqinv[tid - 64] = rsqrtf(fmaxf(nqinv[tid - 64], 1e-24f));
  __syncthreads();

  // ---- P3: KK^T + QK^T MFMA; build KbT & KdT; L/Mq epilogue ----
  f32x4 akk[4], aqk[4];
#pragma unroll
  for (int n = 0; n < 4; ++n) { akk[n] = f32x4{0, 0, 0, 0}; aqk[n] = f32x4{0, 0, 0, 0}; }
  {
    bf16x8 afK[2], afQ[2];
#pragma unroll
    for (int kk = 0; kk < 2; ++kk) {
      afK[kk] = __builtin_bit_cast(bf16x8, *(const u16x8*)&Ks[ar * 64 + swz(ar, kk * 32 + fq * 8)]);
      afQ[kk] = __builtin_bit_cast(bf16x8, qa[kk]);
    }
#pragma unroll
    for (int n = 0; n < 4; ++n) {
      const int br = n * 16 + fr;
#pragma unroll
      for (int kk = 0; kk < 2; ++kk) {
        bf16x8 bk = __builtin_bit_cast(bf16x8, *(const u16x8*)&Ks[br * 64 + swz(br, kk * 32 + fq * 8)]);
        akk[n] = __builtin_amdgcn_mfma_f32_16x16x32_bf16(afK[kk], bk, akk[n], 0, 0, 0);
        aqk[n] = __builtin_amdgcn_mfma_f32_16x16x32_bf16(afQ[kk], bk, aqk[n], 0, 0, 0);
      }
    }
  }
  // KbT[64+j][t] = bA_t k̂[t][j];  KdT[j][t] = 2^(c63-c_t) k̂[t][j]
  {
    const int j = tid & 63, tg4 = tid >> 6;
    const float c63 = cvec[63];
    u16 kb[16], kd[16];
#pragma unroll
    for (int tt = 0; tt < 16; ++tt) {
      int t = tg4 * 16 + tt;
      float kv = bf2f(Ks[t * 64 + swz(t, j)]) * nkinv[t];
      kb[tt] = f2bf(bvec[t] * Avec[t] * kv);
      kd[tt] = f2bf(exp2f(c63 - cvec[t]) * kv);
    }
#pragma unroll
    for (int g8 = 0; g8 < 2; ++g8) {
      u16x8 o1, o2;
#pragma unroll
      for (int e = 0; e < 8; ++e) { o1[e] = kb[g8 * 8 + e]; o2[e] = kd[g8 * 8 + e]; }
      int colg = tg4 * 16 + g8 * 8;
      *(u16x8*)&WTs[(64 + j) * 64 + swz(64 + j, colg)] = o1;
      *(u16x8*)&KdT[j * 64 + swz(j, colg)] = o2;
    }
  }
#pragma unroll
  for (int n = 0; n < 4; ++n)
#pragma unroll
    for (int r = 0; r < 4; ++r) {
      const int t = w * 16 + fq * 4 + r;
      const int s = n * 16 + fr;
      const float e = exp2f(cvec[t] - cvec[s]);
      Lb[t * 64 + swz(t, s)] = (s < t) ? f2bf(bvec[t] * e * nkinv[t] * nkinv[s] * akk[n][r]) : (u16)0;
      MqS[t * 64 + swz(t, s)] = (s <= t) ? f2bf(e * nqinv[t] * nkinv[s] * aqk[n][r]) : (u16)0;
    }
  __syncthreads();

  // ---- P4: Dinv of 4 diagonal 16x16 blocks (wave0, 64 parallel columns) ----
  if (w == 0) {
    const int bi = l >> 4, c = l & 15;
    const int rb = bi * 16;
    float x[16];
#pragma unroll
    for (int u = 0; u < 16; ++u) {
      float a2 = (u == c) ? 1.f : 0.f;
#pragma unroll
      for (int s = 0; s < u; ++s)
        a2 -= bf2f(Lb[(rb + u) * 64 + swz(rb + u, rb + s)]) * x[s];
      x[u] = a2;
    }
#pragma unroll
    for (int u = 0; u < 16; ++u)
      Db[bi * 16 * DBS + u * DBS + c] = f2bf(x[u]);
  }
  __syncthreads();

  // ---- P5: L~ = Dinv.L (scalar, store NEGATED); R~T = RT.DinvT (MFMA) ----
  float ltil[6];
  {
    const int pbi[6] = {1, 2, 2, 3, 3, 3}, pbj[6] = {0, 0, 1, 0, 1, 2};
    const int tt = tid >> 4, s = tid & 15;
#pragma unroll
    for (int e = 0; e < 6; ++e) {
      int bi = pbi[e], bj = pbj[e];
      float a2 = 0.f;
#pragma unroll
      for (int u = 0; u < 16; ++u)
        a2 += bf2f(Db[bi * 16 * DBS + tt * DBS + u]) *
              bf2f(Lb[(bi * 16 + u) * 64 + swz(bi * 16 + u, bj * 16 + s)]);
      ltil[e] = a2;
    }
  }
  f32x4 rtacc[2][4];
#pragma unroll
  for (int rt2 = 0; rt2 < 2; ++rt2) {
    const int rrow = (w * 2 + rt2) * 16 + fr;
#pragma unroll
    for (int bi = 0; bi < 4; ++bi) {
      bf16x8 a2 = (fq < 2)
        ? __builtin_bit_cast(bf16x8, *(const u16x8*)&WTs[rrow * 64 + swz(rrow, bi * 16 + fq * 8)])
        : zfrag();
      bf16x8 b2 = (fq < 2)
        ? __builtin_bit_cast(bf16x8, *(const u16x8*)&Db[bi * 16 * DBS + fr * DBS + fq * 8])
        : zfrag();
      rtacc[rt2][bi] = __builtin_amdgcn_mfma_f32_16x16x32_bf16(a2, b2, f32x4{0, 0, 0, 0}, 0, 0, 0);
    }
  }
  __syncthreads();   // all L~/R~ reads done before overwrites
  {
    const int pbi[6] = {1, 2, 2, 3, 3, 3}, pbj[6] = {0, 0, 1, 0, 1, 2};
    const int tt = tid >> 4, s = tid & 15;
#pragma unroll
    for (int e = 0; e < 6; ++e)
      Lb[(pbi[e] * 16 + tt) * 64 + swz(pbi[e] * 16 + tt, pbj[e] * 16 + s)] = f2bf(-ltil[e]);
  }
#pragma unroll
  for (int rt2 = 0; rt2 < 2; ++rt2)
#pragma unroll
    for (int bi = 0; bi < 4; ++bi)
#pragma unroll
      for (int r = 0; r < 4; ++r) {
        int rr = (w * 2 + rt2) * 16 + fq * 4 + r;
        WTs[rr * 64 + swz(rr, bi * 16 + fr)] = f2bf(rtacc[rt2][bi][r]);
      }
  __syncthreads();

  // ---- P6: 3-step MFMA substitution (row-tiles wave-exclusive, no barriers) ----
#pragma unroll
  for (int rt2 = 0; rt2 < 2; ++rt2) {
    const int rrow = (w * 2 + rt2) * 16 + fr;
    const int wr0 = (w * 2 + rt2) * 16 + fq * 4;
#pragma unroll
    for (int i = 1; i < 4; ++i) {
      f32x4 a2;
#pragma unroll
      for (int r = 0; r < 4; ++r)
        a2[r] = bf2f(WTs[(wr0 + r) * 64 + swz(wr0 + r, i * 16 + fr)]);
      {
        bf16x8 af = __builtin_bit_cast(bf16x8, *(const u16x8*)&WTs[rrow * 64 + swz(rrow, fq * 8)]);
        bf16x8 bf_;
        if (i == 1) bf_ = (fq < 2)
          ? __builtin_bit_cast(bf16x8, *(const u16x8*)&Lb[(16 + fr) * 64 + swz(16 + fr, fq * 8)])
          : zfrag();
        else bf_ = __builtin_bit_cast(bf16x8, *(const u16x8*)&Lb[(i * 16 + fr) * 64 + swz(i * 16 + fr, fq * 8)]);
        a2 = __builtin_amdgcn_mfma_f32_16x16x32_bf16(af, bf_, a2, 0, 0, 0);
      }
      if (i == 3) {
        bf16x8 af = __builtin_bit_cast(bf16x8, *(const u16x8*)&WTs[rrow * 64 + swz(rrow, 32 + fq * 8)]);
        bf16x8 bf_ = (fq < 2)
          ? __builtin_bit_cast(bf16x8, *(const u16x8*)&Lb[(48 + fr) * 64 + swz(48 + fr, 32 + fq * 8)])
          : zfrag();
        a2 = __builtin_amdgcn_mfma_f32_16x16x32_bf16(af, bf_, a2, 0, 0, 0);
      }
#pragma unroll
      for (int r = 0; r < 4; ++r)
        WTs[(wr0 + r) * 64 + swz(wr0 + r, i * 16 + fr)] = f2bf(a2[r]);
    }
  }
  __syncthreads();

  // ---- P7: final 4 GEMMs + in-place swizzled epilogue ----
  u16 qpre[4][4];
#pragma unroll
  for (int n = 0; n < 4; ++n)
#pragma unroll
    for (int r = 0; r < 4; ++r)
      qpre[n][r] = qkv[(t0 + w * 16 + fq * 4 + r) * 3072 + h * 64 + n * 16 + fr];

  f32x4 aG[4], aU[4], aQe[4], aOi[4];
#pragma unroll
  for (int n = 0; n < 4; ++n) {
    aG[n] = f32x4{0, 0, 0, 0}; aU[n] = f32x4{0, 0, 0, 0};
    aQe[n] = f32x4{0, 0, 0, 0}; aOi[n] = f32x4{0, 0, 0, 0};
  }
  {
    bf16x8 aKd[2], aWv[2], aMq[2];
#pragma unroll
    for (int kk = 0; kk < 2; ++kk) {
      aKd[kk] = __builtin_bit_cast(bf16x8, *(const u16x8*)&KdT[ar * 64 + swz(ar, kk * 32 + fq * 8)]);
      aWv[kk] = __builtin_bit_cast(bf16x8, *(const u16x8*)&WTs[ar * 64 + swz(ar, kk * 32 + fq * 8)]);
      aMq[kk] = __builtin_bit_cast(bf16x8, *(const u16x8*)&MqS[ar * 64 + swz(ar, kk * 32 + fq * 8)]);
    }
#pragma unroll
    for (int n = 0; n < 4; ++n) {
      const int br = n * 16 + fr;
#pragma unroll
      for (int kk = 0; kk < 2; ++kk) {
        bf16x8 bTw = __builtin_bit_cast(bf16x8, *(const u16x8*)&WTs[(64 + br) * 64 + swz(64 + br, kk * 32 + fq * 8)]);
        bf16x8 bKd = __builtin_bit_cast(bf16x8, *(const u16x8*)&KdT[br * 64 + swz(br, kk * 32 + fq * 8)]);
        bf16x8 bWv = __builtin_bit_cast(bf16x8, *(const u16x8*)&WTs[br * 64 + swz(br, kk * 32 + fq * 8)]);
        aG[n]  = __builtin_amdgcn_mfma_f32_16x16x32_bf16(aKd[kk], bTw, aG[n], 0, 0, 0);
        aU[n]  = __builtin_amdgcn_mfma_f32_16x16x32_bf16(aWv[kk], bKd, aU[n], 0, 0, 0);
        aQe[n] = __builtin_amdgcn_mfma_f32_16x16x32_bf16(aMq[kk], bTw, aQe[n], 0, 0, 0);
        aOi[n] = __builtin_amdgcn_mfma_f32_16x16x32_bf16(aMq[kk], bWv, aOi[n], 0, 0, 0);
      }
    }
  }
  asm volatile("s_waitcnt vmcnt(0)" ::: "memory");   // qpre loaded before slot overwrite
  __builtin_amdgcn_sched_barrier(0);
#pragma unroll
  for (int n = 0; n < 4; ++n)
#pragma unroll
    for (int r = 0; r < 4; ++r) {
      const int i = w * 16 + fq * 4 + r;
      const int cn = n * 16 + fr;
      const long grow = (t0 + i) * 3072 + h * 64 + swz(i, cn);   // PRE-SWIZZLED
      qkv[grow]        = f2bf(Avec[i] * nqinv[i] * bf2f(qpre[n][r]) - aQe[n][r]);  // Qeff
      qkv[grow + 1024] = f2bf(-aG[n][r]);                                          // G
      qkv[grow + 2048] = f2bf(aU[n][r]);                                           // U
      ob[(t0 + i) * 1024 + h * 64 + cn] = f2bf(aOi[n][r]);                         // O_intra (linear)
    }
}

// ---------------- sequential chunk recurrence (double-buffered async staging) --
__global__ __launch_bounds__(256) void k_seq(const u16* __restrict__ qkv,
                                             const float* __restrict__ A63G,
                                             u16* __restrict__ ob) {
  __shared__ __align__(16) u16 Sb[64 * 64];
  __shared__ __align__(16) u16 stg[2][4][64 * 64];   // [buf][Qe,G,U,Ob][..]
  __shared__ float a63s[64];
  const int pair = blockIdx.x;
  const int b = pair >> 4, h = pair & 15;
  const int tid = threadIdx.x, l = tid & 63, w = tid >> 6;
  const int fr = l & 15, fq = l >> 4;
  const int ar = w * 16 + fr;

  auto stage = [&](int c, int bi) {
    const long tg = (long)b * NT + (long)c * CC;
#pragma unroll
    for (int m = 0; m < 4; ++m)
#pragma unroll
      for (int p = 0; p < 2; ++p) {
        int idx = p * 256 + tid;
        int row = idx >> 3, seg = (idx & 7) * 8;
        const u16* src = (m < 3)
          ? &qkv[(tg + row) * 3072 + m * 1024 + h * 64 + seg]
          : &ob[(tg + row) * 1024 + h * 64 + seg];
        gload_lds16(src, &stg[bi][m][p * 2048 + w * 512]);
      }
  };

  if (tid < 64) a63s[tid] = A63G[pair * 64 + tid];
  for (int i = tid; i < 4096; i += 256) Sb[i] = 0;
  stage(0, 0);
  f32x4 sacc[4];
#pragma unroll
  for (int n = 0; n < 4; ++n) sacc[n] = f32x4{0, 0, 0, 0};
  asm volatile("s_waitcnt lgkmcnt(0)" ::: "memory");
  __builtin_amdgcn_sched_barrier(0);

  for (int c = 0; c < NCH; ++c) {
    const int bi = c & 1;
    const long tg = (long)b * NT + (long)c * CC;
    if (c + 1 < NCH) {
      stage(c + 1, bi ^ 1);
      asm volatile("s_waitcnt vmcnt(8)" ::: "memory");
    } else {
      asm volatile("s_waitcnt vmcnt(0)" ::: "memory");
    }
    __builtin_amdgcn_sched_barrier(0);
    __builtin_amdgcn_s_barrier();
    __builtin_amdgcn_sched_barrier(0);

    const u16* Qe = stg[bi][0];
    const u16* Gm = stg[bi][1];
    const u16* Um = stg[bi][2];
    const u16* Obl = stg[bi][3];

    // O_cross[t][d] = sum_j Qeff[t][j] S[d][j]
    bf16x8 aq[2];
#pragma unroll
    for (int kk = 0; kk < 2; ++kk)
      aq[kk] = __builtin_bit_cast(bf16x8, *(const u16x8*)&Qe[ar * 64 + swz(ar, kk * 32 + fq * 8)]);
    f32x4 ao[4];
#pragma unroll
    for (int n = 0; n < 4; ++n) ao[n] = f32x4{0, 0, 0, 0};
#pragma unroll
    for (int n = 0; n < 4; ++n) {
      const int br = n * 16 + fr;
#pragma unroll
      for (int kk = 0; kk < 2; ++kk) {
        bf16x8 sb = __builtin_bit_cast(bf16x8, *(const u16x8*)&Sb[br * 64 + swz(br, kk * 32 + fq * 8)]);
        ao[n] = __builtin_amdgcn_mfma_f32_16x16x32_bf16(aq[kk], sb, ao[n], 0, 0, 0);
      }
    }
    // S update: sacc = A63*sacc + S.G (+U below)
    bf16x8 as_[2];
#pragma unroll
    for (int kk = 0; kk < 2; ++kk)
      as_[kk] = __builtin_bit_cast(bf16x8, *(const u16x8*)&Sb[ar * 64 + swz(ar, kk * 32 + fq * 8)]);
    const float A63 = a63s[c];
#pragma unroll
    for (int n = 0; n < 4; ++n) {
#pragma unroll
      for (int r = 0; r < 4; ++r) sacc[n][r] *= A63;
      const int br = n * 16 + fr;
#pragma unroll
      for (int kk = 0; kk < 2; ++kk) {
        bf16x8 g = __builtin_bit_cast(bf16x8, *(const u16x8*)&Gm[br * 64 + swz(br, kk * 32 + fq * 8)]);
        sacc[n] = __builtin_amdgcn_mfma_f32_16x16x32_bf16(as_[kk], g, sacc[n], 0, 0, 0);
      }
    }
    // +U, O writeout
#pragma unroll
    for (int n = 0; n < 4; ++n)
#pragma unroll
      for (int r = 0; r < 4; ++r) {
        const int i = w * 16 + fq * 4 + r;
        const int cn = n * 16 + fr;
        sacc[n][r] += bf2f(Um[i * 64 + swz(i, cn)]);
        float o = bf2f(Obl[i * 64 + cn]) + ao[n][r];
        ob[(tg + i) * 1024 + h * 64 + cn] = f2bf(o);
      }
    __builtin_amdgcn_s_barrier();   // all waves done reading Sb
#pragma unroll
    for (int n = 0; n < 4; ++n)
#pragma unroll
      for (int r = 0; r < 4; ++r) {
        const int d = w * 16 + fq * 4 + r, j = n * 16 + fr;
        Sb[d * 64 + swz(d, j)] = f2bf(sacc[n][r]);
      }
    asm volatile("s_waitcnt lgkmcnt(0)" ::: "memory");
    __builtin_amdgcn_sched_barrier(0);
  }
}

extern "C" void kernel_launch(void* const* d_in, const int* in_sizes, int n_in,
                              void* d_out, int out_size, void* d_ws, size_t ws_size,
                              hipStream_t stream) {
  const float* x    = (const float*)d_in[0];
  const float* Wqkv = (const float*)d_in[1];
  const float* Wg   = (const float*)d_in[2];
  const float* bg   = (const float*)d_in[3];
  const float* Wb   = (const float*)d_in[4];
  const float* bb   = (const float*)d_in[5];
  const float* Wout = (const float*)d_in[6];
  float* out = (float*)d_out;

  char* ws = (char*)d_ws;
  u16* xb    = (u16*)ws;                               // 16384*1024   (32MB)
  u16* wqkvb = xb    + (long)BT * NDIM;                // 3072*1024    (6MB)
  u16* woutb = wqkvb + (long)3072 * 1024;              // 1024*1024    (2MB)
  u16* wgbb  = woutb + (long)1024 * 1024;              // 128*1024
  u16* qkvb  = wgbb  + (long)128 * 1024;               // 16384*3072   (96MB)
  u16* ob    = qkvb  + (long)BT * 3072;                // 16384*1024   (32MB)
  float* graw  = (float*)(ob + (long)BT * NDIM);       // 16384*128    (8MB)
  float* alpha = graw + (long)BT * 128;                // 16384*16     (1MB)
  float* beta  = alpha + (long)BT * NH;                // 16384*16     (1MB)
  float* A63G  = graw;   // reuse: graw dead after k_gates_fin (needs 16KB)

  // 1. converts
  k_f32_to_bf16<<<(BT * (long)NDIM / 4 + 255) / 256, 256, 0, stream>>>(x, xb, BT * (long)NDIM / 4);
  k_f32_to_bf16<<<(3072L * 1024 / 4 + 255) / 256, 256, 0, stream>>>(Wqkv, wqkvb, 3072L * 1024 / 4);
  k_f32_to_bf16<<<(1024L * 1024 / 4 + 255) / 256, 256, 0, stream>>>(Wout, woutb, 1024L * 1024 / 4);
  k_build_wgb<<<(128 * 1024) / 256, 256, 0, stream>>>(Wg, Wb, wgbb);

  // 2. qkv GEMM (256^2 8-phase): 16384x3072 = xb @ wqkvb^T
  k_gemm256<u16><<<64 * 12, 512, 0, stream>>>(xb, wqkvb, qkvb, BT, 3072, NDIM);

  // 3. gates GEMM (N=128, old path) + finalize
  k_gemm_bt<float><<<dim3(1, BT / 128), 256, 0, stream>>>(xb, wgbb, graw, BT, 128, NDIM);
  k_gates_fin<<<(BT * NH + 255) / 256, 256, 0, stream>>>(graw, bg, bb, alpha, beta);

  // 4. chunked WY: parallel precompute (fused l2norm, MFMA solve) + sequential GEMMs
  k_prep<<<NU, 256, 0, stream>>>(qkvb, alpha, beta, A63G, ob);
  k_seq<<<NPAIR, 256, 0, stream>>>(qkvb, A63G, ob);

  // 5. out GEMM (256^2 8-phase): 16384x1024 = ob @ woutb^T (fp32 out)
  k_gemm256<float><<<64 * 4, 512, 0, stream>>>(ob, woutb, out, BT, NDIM, NDIM);
}